// Round 1
// baseline (1136.835 us; speedup 1.0000x reference)
//
#include <hip/hip_runtime.h>
#include <math.h>

#define ED 128

// ---------------- encoder: h = tanh(x @ enc_W + enc_b), x:[n,2] ----------------
__global__ __launch_bounds__(256) void encoder_kernel(
    const float* __restrict__ x, const float* __restrict__ W,
    const float* __restrict__ b, float* __restrict__ h, int n) {
  int idx = blockIdx.x * blockDim.x + threadIdx.x;
  if (idx >= n * ED) return;
  int i = idx >> 7, c = idx & 127;
  float v = x[i * 2 + 0] * W[c] + x[i * 2 + 1] * W[ED + c] + b[c];
  h[idx] = tanhf(v);
}

// ---------------- CSR build ----------------
__global__ __launch_bounds__(256) void count_deg_kernel(
    const int* __restrict__ dst, int* __restrict__ deg, int E) {
  int e = blockIdx.x * blockDim.x + threadIdx.x;
  if (e < E) atomicAdd(&deg[dst[e]], 1);
}

__global__ __launch_bounds__(1024) void scan_kernel(
    const int* __restrict__ deg, int* __restrict__ offs,
    int* __restrict__ cursor, int n) {
  __shared__ int wsum[16];
  __shared__ int carry_s;
  const int tid = threadIdx.x;
  const int lane = tid & 63;
  const int wid = tid >> 6;
  if (tid == 0) carry_s = 0;
  __syncthreads();
  for (int base = 0; base < n; base += 1024) {
    const int i = base + tid;
    const int v = (i < n) ? deg[i] : 0;
    int x = v;
    #pragma unroll
    for (int d = 1; d < 64; d <<= 1) {
      int t = __shfl_up(x, d, 64);
      if (lane >= d) x += t;
    }
    if (lane == 63) wsum[wid] = x;
    __syncthreads();
    int wbase = 0, total = 0;
    #pragma unroll
    for (int w = 0; w < 16; ++w) {
      int s = wsum[w];
      if (w < wid) wbase += s;
      total += s;
    }
    const int carry = carry_s;
    if (i < n) {
      const int excl = carry + wbase + x - v;
      offs[i] = excl;
      cursor[i] = excl;
    }
    __syncthreads();
    if (tid == 0) carry_s = carry + total;
    __syncthreads();
  }
  if (tid == 0) offs[n] = carry_s;
}

__global__ __launch_bounds__(256) void scatter_kernel(
    const int* __restrict__ src, const int* __restrict__ dst,
    int* __restrict__ cursor, int* __restrict__ ssrc, int E) {
  int e = blockIdx.x * blockDim.x + threadIdx.x;
  if (e < E) {
    int d = dst[e];
    int pos = atomicAdd(&cursor[d], 1);
    ssrc[pos] = src[e];
  }
}

// ---------------- node GEMM: C = act(A1 @ W[0:128] (+ A2 @ W[128:256]) + b) ----
// A1,A2: [n,128], W: [KSEG*128, 128] row-major, C: [n,128]
template <int KSEG>
__global__ __launch_bounds__(256) void gemm_node_kernel(
    const float* __restrict__ A1, const float* __restrict__ A2,
    const float* __restrict__ W, const float* __restrict__ bias,
    float* __restrict__ C, int n, int do_tanh) {
  __shared__ float As[32][32];
  __shared__ float Ws[32][128];
  const int tid = threadIdx.x;
  const int ty = tid >> 5;   // 0..7
  const int tx = tid & 31;   // 0..31
  const int row0 = blockIdx.x * 32;

  float acc[4][4] = {};

  for (int seg = 0; seg < KSEG; ++seg) {
    const float* __restrict__ A = (seg == 0) ? A1 : A2;
    for (int k0 = 0; k0 < ED; k0 += 32) {
      // stage A tile [32 rows x 32 k]
      {
        int r = tid >> 3, kq = tid & 7;
        int grow = row0 + r;
        if (grow >= n) grow = n - 1;
        float4 av = *reinterpret_cast<const float4*>(A + (size_t)grow * ED + k0 + kq * 4);
        *reinterpret_cast<float4*>(&As[r][kq * 4]) = av;
      }
      // stage W tile [32 k x 128 cols]
      #pragma unroll
      for (int j = 0; j < 4; ++j) {
        int lin = tid + j * 256;          // float4 index 0..1023
        int r = lin >> 5, c4 = lin & 31;
        *reinterpret_cast<float4*>(&Ws[r][c4 * 4]) =
            *reinterpret_cast<const float4*>(W + (size_t)(seg * ED + k0 + r) * ED + c4 * 4);
      }
      __syncthreads();
      #pragma unroll
      for (int kk = 0; kk < 32; ++kk) {
        float a0 = As[ty * 4 + 0][kk];
        float a1 = As[ty * 4 + 1][kk];
        float a2 = As[ty * 4 + 2][kk];
        float a3 = As[ty * 4 + 3][kk];
        float4 w = *reinterpret_cast<const float4*>(&Ws[kk][tx * 4]);
        acc[0][0] += a0 * w.x; acc[0][1] += a0 * w.y; acc[0][2] += a0 * w.z; acc[0][3] += a0 * w.w;
        acc[1][0] += a1 * w.x; acc[1][1] += a1 * w.y; acc[1][2] += a1 * w.z; acc[1][3] += a1 * w.w;
        acc[2][0] += a2 * w.x; acc[2][1] += a2 * w.y; acc[2][2] += a2 * w.z; acc[2][3] += a2 * w.w;
        acc[3][0] += a3 * w.x; acc[3][1] += a3 * w.y; acc[3][2] += a3 * w.z; acc[3][3] += a3 * w.w;
      }
      __syncthreads();
    }
  }

  float4 bv = *reinterpret_cast<const float4*>(bias + tx * 4);
  #pragma unroll
  for (int r = 0; r < 4; ++r) {
    int grow = row0 + ty * 4 + r;
    if (grow < n) {
      float4 o;
      o.x = acc[r][0] + bv.x;
      o.y = acc[r][1] + bv.y;
      o.z = acc[r][2] + bv.z;
      o.w = acc[r][3] + bv.w;
      if (do_tanh) { o.x = tanhf(o.x); o.y = tanhf(o.y); o.z = tanhf(o.z); o.w = tanhf(o.w); }
      *reinterpret_cast<float4*>(C + (size_t)grow * ED + tx * 4) = o;
    }
  }
}

// ---------------- edge aggregation: per-dst segment softmax + weighted sum ----
// one block (128 threads) per dst node; thread = channel
__global__ __launch_bounds__(128) void edge_aggr_kernel(
    const int* __restrict__ offs, const int* __restrict__ ssrc,
    const float* __restrict__ G, const float* __restrict__ V,
    float* __restrict__ aggr, int n) {
  int i = blockIdx.x;
  if (i >= n) return;
  int c = threadIdx.x;
  int s0 = offs[i], s1 = offs[i + 1];

  float m = -INFINITY;
  for (int e = s0; e < s1; ++e) {
    int s = ssrc[e];
    m = fmaxf(m, G[(size_t)s * ED + c]);
  }
  if (!isfinite(m)) m = 0.0f;  // deg==0 case (matches reference)

  float sum = 0.0f, acc = 0.0f;
  for (int e = s0; e < s1; ++e) {
    int s = ssrc[e];
    float w = __expf(G[(size_t)s * ED + c] - m);
    sum += w;
    acc += w * V[(size_t)s * ED + c];
  }
  aggr[(size_t)i * ED + c] = acc / (sum + 1e-16f);
}

// ---------------- decoder: out = tanh(h @ W1 + b1) @ W2 + b2 ----------------
__global__ __launch_bounds__(256) void decoder_kernel(
    const float* __restrict__ h, const float* __restrict__ W1,
    const float* __restrict__ b1, const float* __restrict__ W2,
    const float* __restrict__ b2, float* __restrict__ out, int n) {
  __shared__ float Ws[ED * 64];
  for (int j = threadIdx.x; j < ED * 64; j += 256) Ws[j] = W1[j];
  __syncthreads();
  int node = blockIdx.x * 4 + (threadIdx.x >> 6);
  int t = threadIdx.x & 63;
  if (node >= n) return;
  const float* hr = h + (size_t)node * ED;
  float acc = b1[t];
  #pragma unroll 8
  for (int k = 0; k < ED; ++k) acc += hr[k] * Ws[k * 64 + t];
  float u = tanhf(acc) * W2[t];
  #pragma unroll
  for (int off = 32; off > 0; off >>= 1) u += __shfl_down(u, off, 64);
  if (t == 0) out[node] = u + b2[0];
}

// ---------------- host ----------------
extern "C" void kernel_launch(void* const* d_in, const int* in_sizes, int n_in,
                              void* d_out, int out_size, void* d_ws, size_t ws_size,
                              hipStream_t stream) {
  const float* node_feature = (const float*)d_in[0];
  const int*   edge_index   = (const int*)d_in[1];
  const float* enc_W  = (const float*)d_in[3];
  const float* enc_b  = (const float*)d_in[4];
  const float* gate_W = (const float*)d_in[5];
  const float* gate_b = (const float*)d_in[6];
  const float* att_W  = (const float*)d_in[7];
  const float* att_b  = (const float*)d_in[8];
  const float* msg_W  = (const float*)d_in[9];
  const float* msg_b  = (const float*)d_in[10];
  const float* upd_W  = (const float*)d_in[11];
  const float* upd_b  = (const float*)d_in[12];
  const float* dec1_W = (const float*)d_in[13];
  const float* dec1_b = (const float*)d_in[14];
  const float* dec2_W = (const float*)d_in[15];
  const float* dec2_b = (const float*)d_in[16];

  const int n = in_sizes[0] / 2;   // 50000
  const int E = in_sizes[1] / 2;   // 800000
  const int* src = edge_index;
  const int* dst = edge_index + E;

  char* ws = (char*)d_ws;
  size_t off = 0;
  auto alloc = [&](size_t bytes) -> void* {
    void* p = ws + off;
    off += (bytes + 255) & ~(size_t)255;
    return p;
  };
  float* hA   = (float*)alloc((size_t)n * ED * 4);
  float* hB   = (float*)alloc((size_t)n * ED * 4);
  float* G    = (float*)alloc((size_t)n * ED * 4);
  float* V    = (float*)alloc((size_t)n * ED * 4);
  float* aggr = (float*)alloc((size_t)n * ED * 4);
  int* deg    = (int*)alloc((size_t)n * 4);
  int* offs   = (int*)alloc((size_t)(n + 1) * 4);
  int* cursor = (int*)alloc((size_t)n * 4);
  int* ssrc   = (int*)alloc((size_t)E * 4);

  // CSR build (once per call; same for all layers)
  hipMemsetAsync(deg, 0, (size_t)n * 4, stream);
  count_deg_kernel<<<(E + 255) / 256, 256, 0, stream>>>(dst, deg, E);
  scan_kernel<<<1, 1024, 0, stream>>>(deg, offs, cursor, n);
  scatter_kernel<<<(E + 255) / 256, 256, 0, stream>>>(src, dst, cursor, ssrc, E);

  // encoder
  encoder_kernel<<<((size_t)n * ED + 255) / 256, 256, 0, stream>>>(
      node_feature, enc_W, enc_b, hA, n);

  float* h = hA;
  float* scratch = hB;
  const int gemm_grid = (n + 31) / 32;

  for (int l = 0; l < 3; ++l) {
    const float* mW = msg_W + (size_t)l * ED * ED;
    const float* mb = msg_b + (size_t)l * ED;
    const float* gW = gate_W + (size_t)l * ED * ED;
    const float* gb = gate_b + (size_t)l * ED;
    const float* aW = att_W + (size_t)l * ED * ED;
    const float* ab = att_b + (size_t)l * ED;
    const float* uW = upd_W + (size_t)l * 2 * ED * ED;
    const float* ub = upd_b + (size_t)l * ED;

    float* M = scratch;
    // M = tanh(h @ msg_W + msg_b)
    gemm_node_kernel<1><<<gemm_grid, 256, 0, stream>>>(h, nullptr, mW, mb, M, n, 1);
    // G = M @ gate_W + gate_b
    gemm_node_kernel<1><<<gemm_grid, 256, 0, stream>>>(M, nullptr, gW, gb, G, n, 0);
    // V = tanh(M @ att_W + att_b)
    gemm_node_kernel<1><<<gemm_grid, 256, 0, stream>>>(M, nullptr, aW, ab, V, n, 1);
    // aggr = segment-softmax-weighted sum
    edge_aggr_kernel<<<n, 128, 0, stream>>>(offs, ssrc, G, V, aggr, n);
    // h_new = tanh([h, aggr] @ upd_W + upd_b)  -> overwrite M (dead)
    gemm_node_kernel<2><<<gemm_grid, 256, 0, stream>>>(h, aggr, uW, ub, M, n, 1);
    // swap
    float* tmp = h; h = M; scratch = tmp;
  }

  decoder_kernel<<<(n + 3) / 4, 256, 0, stream>>>(
      h, dec1_W, dec1_b, dec2_W, dec2_b, (float*)d_out, n);
}

// Round 2
// 971.039 us; speedup vs baseline: 1.1707x; 1.1707x over previous
//
#include <hip/hip_runtime.h>
#include <math.h>

#define ED 128
// packed per-node row: 128 fp32 G (512B) + 128 bf16 V (256B) = 768B
#define PSTRIDE 768

static __device__ __forceinline__ float bf2f(unsigned short u) {
  union { float f; unsigned int i; } p;
  p.i = ((unsigned int)u) << 16;
  return p.f;
}
static __device__ __forceinline__ unsigned short f2bf(float f) {
  union { float f; unsigned int i; } p;
  p.f = f;
  unsigned int x = p.i;
  unsigned int r = x + 0x7fffu + ((x >> 16) & 1u);  // RNE
  return (unsigned short)(r >> 16);
}

// ---------------- encoder: h = tanh(x @ enc_W + enc_b), x:[n,2] ----------------
__global__ __launch_bounds__(256) void encoder_kernel(
    const float* __restrict__ x, const float* __restrict__ W,
    const float* __restrict__ b, float* __restrict__ h, int n) {
  int idx = blockIdx.x * blockDim.x + threadIdx.x;
  if (idx >= n * ED) return;
  int i = idx >> 7, c = idx & 127;
  float v = x[i * 2 + 0] * W[c] + x[i * 2 + 1] * W[ED + c] + b[c];
  h[idx] = tanhf(v);
}

// ---------------- CSR build ----------------
__global__ __launch_bounds__(256) void count_deg_kernel(
    const int* __restrict__ dst, int* __restrict__ deg, int E) {
  int e = blockIdx.x * blockDim.x + threadIdx.x;
  if (e < E) atomicAdd(&deg[dst[e]], 1);
}

__global__ __launch_bounds__(1024) void scan_kernel(
    const int* __restrict__ deg, int* __restrict__ offs,
    int* __restrict__ cursor, int n) {
  __shared__ int wsum[16];
  __shared__ int carry_s;
  const int tid = threadIdx.x;
  const int lane = tid & 63;
  const int wid = tid >> 6;
  if (tid == 0) carry_s = 0;
  __syncthreads();
  for (int base = 0; base < n; base += 1024) {
    const int i = base + tid;
    const int v = (i < n) ? deg[i] : 0;
    int x = v;
    #pragma unroll
    for (int d = 1; d < 64; d <<= 1) {
      int t = __shfl_up(x, d, 64);
      if (lane >= d) x += t;
    }
    if (lane == 63) wsum[wid] = x;
    __syncthreads();
    int wbase = 0, total = 0;
    #pragma unroll
    for (int w = 0; w < 16; ++w) {
      int s = wsum[w];
      if (w < wid) wbase += s;
      total += s;
    }
    const int carry = carry_s;
    if (i < n) {
      const int excl = carry + wbase + x - v;
      offs[i] = excl;
      cursor[i] = excl;
    }
    __syncthreads();
    if (tid == 0) carry_s = carry + total;
    __syncthreads();
  }
  if (tid == 0) offs[n] = carry_s;
}

__global__ __launch_bounds__(256) void scatter_kernel(
    const int* __restrict__ src, const int* __restrict__ dst,
    int* __restrict__ cursor, int* __restrict__ ssrc, int E) {
  int e = blockIdx.x * blockDim.x + threadIdx.x;
  if (e < E) {
    int d = dst[e];
    int pos = atomicAdd(&cursor[d], 1);
    ssrc[pos] = src[e];
  }
}

// ---------------- node GEMM (upd): C = tanh(A1@W[0:128] + A2@W[128:256] + b) --
template <int KSEG>
__global__ __launch_bounds__(256) void gemm_node_kernel(
    const float* __restrict__ A1, const float* __restrict__ A2,
    const float* __restrict__ W, const float* __restrict__ bias,
    float* __restrict__ C, int n, int do_tanh) {
  __shared__ float As[32][32];
  __shared__ float Ws[32][128];
  const int tid = threadIdx.x;
  const int ty = tid >> 5;
  const int tx = tid & 31;
  const int row0 = blockIdx.x * 32;

  float acc[4][4] = {};

  for (int seg = 0; seg < KSEG; ++seg) {
    const float* __restrict__ A = (seg == 0) ? A1 : A2;
    for (int k0 = 0; k0 < ED; k0 += 32) {
      {
        int r = tid >> 3, kq = tid & 7;
        int grow = row0 + r;
        if (grow >= n) grow = n - 1;
        float4 av = *reinterpret_cast<const float4*>(A + (size_t)grow * ED + k0 + kq * 4);
        *reinterpret_cast<float4*>(&As[r][kq * 4]) = av;
      }
      #pragma unroll
      for (int j = 0; j < 4; ++j) {
        int lin = tid + j * 256;
        int r = lin >> 5, c4 = lin & 31;
        *reinterpret_cast<float4*>(&Ws[r][c4 * 4]) =
            *reinterpret_cast<const float4*>(W + (size_t)(seg * ED + k0 + r) * ED + c4 * 4);
      }
      __syncthreads();
      #pragma unroll
      for (int kk = 0; kk < 32; ++kk) {
        float a0 = As[ty * 4 + 0][kk];
        float a1 = As[ty * 4 + 1][kk];
        float a2 = As[ty * 4 + 2][kk];
        float a3 = As[ty * 4 + 3][kk];
        float4 w = *reinterpret_cast<const float4*>(&Ws[kk][tx * 4]);
        acc[0][0] += a0 * w.x; acc[0][1] += a0 * w.y; acc[0][2] += a0 * w.z; acc[0][3] += a0 * w.w;
        acc[1][0] += a1 * w.x; acc[1][1] += a1 * w.y; acc[1][2] += a1 * w.z; acc[1][3] += a1 * w.w;
        acc[2][0] += a2 * w.x; acc[2][1] += a2 * w.y; acc[2][2] += a2 * w.z; acc[2][3] += a2 * w.w;
        acc[3][0] += a3 * w.x; acc[3][1] += a3 * w.y; acc[3][2] += a3 * w.z; acc[3][3] += a3 * w.w;
      }
      __syncthreads();
    }
  }

  float4 bv = *reinterpret_cast<const float4*>(bias + tx * 4);
  #pragma unroll
  for (int r = 0; r < 4; ++r) {
    int grow = row0 + ty * 4 + r;
    if (grow < n) {
      float4 o;
      o.x = acc[r][0] + bv.x;
      o.y = acc[r][1] + bv.y;
      o.z = acc[r][2] + bv.z;
      o.w = acc[r][3] + bv.w;
      if (do_tanh) { o.x = tanhf(o.x); o.y = tanhf(o.y); o.z = tanhf(o.z); o.w = tanhf(o.w); }
      *reinterpret_cast<float4*>(C + (size_t)grow * ED + tx * 4) = o;
    }
  }
}

// ---------------- fused MGV: M=tanh(h@mW+mb) (LDS only);
//                  G=M@gW+gb (fp32), V=tanh(M@aW+ab) (bf16), packed into P ----
__global__ __launch_bounds__(256) void gemm_mgv_kernel(
    const float* __restrict__ h,
    const float* __restrict__ mW, const float* __restrict__ mb,
    const float* __restrict__ gW, const float* __restrict__ gb,
    const float* __restrict__ aW, const float* __restrict__ ab,
    char* __restrict__ P, int n) {
  __shared__ float As[32][32];
  __shared__ float Ms[32][132];   // padded, 16B-aligned rows (132*4=528)
  __shared__ float Ws[32][128];
  const int tid = threadIdx.x;
  const int ty = tid >> 5;
  const int tx = tid & 31;
  const int row0 = blockIdx.x * 32;

  // ---- phase 1: M tile = tanh(h @ mW + mb) -> Ms ----
  {
    float acc[4][4] = {};
    for (int k0 = 0; k0 < ED; k0 += 32) {
      {
        int r = tid >> 3, kq = tid & 7;
        int grow = row0 + r;
        if (grow >= n) grow = n - 1;
        float4 av = *reinterpret_cast<const float4*>(h + (size_t)grow * ED + k0 + kq * 4);
        *reinterpret_cast<float4*>(&As[r][kq * 4]) = av;
      }
      #pragma unroll
      for (int j = 0; j < 4; ++j) {
        int lin = tid + j * 256;
        int r = lin >> 5, c4 = lin & 31;
        *reinterpret_cast<float4*>(&Ws[r][c4 * 4]) =
            *reinterpret_cast<const float4*>(mW + (size_t)(k0 + r) * ED + c4 * 4);
      }
      __syncthreads();
      #pragma unroll
      for (int kk = 0; kk < 32; ++kk) {
        float a0 = As[ty * 4 + 0][kk];
        float a1 = As[ty * 4 + 1][kk];
        float a2 = As[ty * 4 + 2][kk];
        float a3 = As[ty * 4 + 3][kk];
        float4 w = *reinterpret_cast<const float4*>(&Ws[kk][tx * 4]);
        acc[0][0] += a0 * w.x; acc[0][1] += a0 * w.y; acc[0][2] += a0 * w.z; acc[0][3] += a0 * w.w;
        acc[1][0] += a1 * w.x; acc[1][1] += a1 * w.y; acc[1][2] += a1 * w.z; acc[1][3] += a1 * w.w;
        acc[2][0] += a2 * w.x; acc[2][1] += a2 * w.y; acc[2][2] += a2 * w.z; acc[2][3] += a2 * w.w;
        acc[3][0] += a3 * w.x; acc[3][1] += a3 * w.y; acc[3][2] += a3 * w.z; acc[3][3] += a3 * w.w;
      }
      __syncthreads();
    }
    float4 bv = *reinterpret_cast<const float4*>(mb + tx * 4);
    #pragma unroll
    for (int r = 0; r < 4; ++r) {
      float4 o;
      o.x = tanhf(acc[r][0] + bv.x);
      o.y = tanhf(acc[r][1] + bv.y);
      o.z = tanhf(acc[r][2] + bv.z);
      o.w = tanhf(acc[r][3] + bv.w);
      *reinterpret_cast<float4*>(&Ms[ty * 4 + r][tx * 4]) = o;
    }
    __syncthreads();
  }

  // ---- phase 2: G = Ms @ gW + gb -> P (fp32) ----
  {
    float acc[4][4] = {};
    for (int k0 = 0; k0 < ED; k0 += 32) {
      #pragma unroll
      for (int j = 0; j < 4; ++j) {
        int lin = tid + j * 256;
        int r = lin >> 5, c4 = lin & 31;
        *reinterpret_cast<float4*>(&Ws[r][c4 * 4]) =
            *reinterpret_cast<const float4*>(gW + (size_t)(k0 + r) * ED + c4 * 4);
      }
      __syncthreads();
      #pragma unroll
      for (int kk = 0; kk < 32; ++kk) {
        float a0 = Ms[ty * 4 + 0][k0 + kk];
        float a1 = Ms[ty * 4 + 1][k0 + kk];
        float a2 = Ms[ty * 4 + 2][k0 + kk];
        float a3 = Ms[ty * 4 + 3][k0 + kk];
        float4 w = *reinterpret_cast<const float4*>(&Ws[kk][tx * 4]);
        acc[0][0] += a0 * w.x; acc[0][1] += a0 * w.y; acc[0][2] += a0 * w.z; acc[0][3] += a0 * w.w;
        acc[1][0] += a1 * w.x; acc[1][1] += a1 * w.y; acc[1][2] += a1 * w.z; acc[1][3] += a1 * w.w;
        acc[2][0] += a2 * w.x; acc[2][1] += a2 * w.y; acc[2][2] += a2 * w.z; acc[2][3] += a2 * w.w;
        acc[3][0] += a3 * w.x; acc[3][1] += a3 * w.y; acc[3][2] += a3 * w.z; acc[3][3] += a3 * w.w;
      }
      __syncthreads();
    }
    float4 bv = *reinterpret_cast<const float4*>(gb + tx * 4);
    #pragma unroll
    for (int r = 0; r < 4; ++r) {
      int grow = row0 + ty * 4 + r;
      if (grow < n) {
        float4 o;
        o.x = acc[r][0] + bv.x;
        o.y = acc[r][1] + bv.y;
        o.z = acc[r][2] + bv.z;
        o.w = acc[r][3] + bv.w;
        *reinterpret_cast<float4*>(P + (size_t)grow * PSTRIDE + tx * 16) = o;
      }
    }
  }

  // ---- phase 3: V = tanh(Ms @ aW + ab) -> P (bf16) ----
  {
    float acc[4][4] = {};
    for (int k0 = 0; k0 < ED; k0 += 32) {
      #pragma unroll
      for (int j = 0; j < 4; ++j) {
        int lin = tid + j * 256;
        int r = lin >> 5, c4 = lin & 31;
        *reinterpret_cast<float4*>(&Ws[r][c4 * 4]) =
            *reinterpret_cast<const float4*>(aW + (size_t)(k0 + r) * ED + c4 * 4);
      }
      __syncthreads();
      #pragma unroll
      for (int kk = 0; kk < 32; ++kk) {
        float a0 = Ms[ty * 4 + 0][k0 + kk];
        float a1 = Ms[ty * 4 + 1][k0 + kk];
        float a2 = Ms[ty * 4 + 2][k0 + kk];
        float a3 = Ms[ty * 4 + 3][k0 + kk];
        float4 w = *reinterpret_cast<const float4*>(&Ws[kk][tx * 4]);
        acc[0][0] += a0 * w.x; acc[0][1] += a0 * w.y; acc[0][2] += a0 * w.z; acc[0][3] += a0 * w.w;
        acc[1][0] += a1 * w.x; acc[1][1] += a1 * w.y; acc[1][2] += a1 * w.z; acc[1][3] += a1 * w.w;
        acc[2][0] += a2 * w.x; acc[2][1] += a2 * w.y; acc[2][2] += a2 * w.z; acc[2][3] += a2 * w.w;
        acc[3][0] += a3 * w.x; acc[3][1] += a3 * w.y; acc[3][2] += a3 * w.z; acc[3][3] += a3 * w.w;
      }
      __syncthreads();
    }
    float4 bv = *reinterpret_cast<const float4*>(ab + tx * 4);
    #pragma unroll
    for (int r = 0; r < 4; ++r) {
      int grow = row0 + ty * 4 + r;
      if (grow < n) {
        ushort4 o;
        o.x = f2bf(tanhf(acc[r][0] + bv.x));
        o.y = f2bf(tanhf(acc[r][1] + bv.y));
        o.z = f2bf(tanhf(acc[r][2] + bv.z));
        o.w = f2bf(tanhf(acc[r][3] + bv.w));
        *reinterpret_cast<ushort4*>(P + (size_t)grow * PSTRIDE + 512 + tx * 8) = o;
      }
    }
  }
}

// ---------------- edge aggregation: single-pass online segment softmax -------
// one block (128 threads) per dst node; thread = channel
__global__ __launch_bounds__(128) void edge_aggr2_kernel(
    const int* __restrict__ offs, const int* __restrict__ ssrc,
    const char* __restrict__ P, float* __restrict__ aggr, int n) {
  int i = blockIdx.x;
  if (i >= n) return;
  int c = threadIdx.x;
  int s0 = offs[i], s1 = offs[i + 1];

  float m = -INFINITY, s = 0.0f, a = 0.0f;
  for (int e = s0; e < s1; ++e) {
    int sn = ssrc[e];
    const char* row = P + (size_t)sn * PSTRIDE;
    float g = *reinterpret_cast<const float*>(row + c * 4);
    float v = bf2f(*reinterpret_cast<const unsigned short*>(row + 512 + c * 2));
    float nm = fmaxf(m, g);
    float f = __expf(m - nm);   // first iter: exp(-inf)=0 zeroes the (empty) state
    float w = __expf(g - nm);
    s = s * f + w;
    a = a * f + w * v;
    m = nm;
  }
  aggr[(size_t)i * ED + c] = a / (s + 1e-16f);
}

// ---------------- decoder: out = tanh(h @ W1 + b1) @ W2 + b2 ----------------
__global__ __launch_bounds__(256) void decoder_kernel(
    const float* __restrict__ h, const float* __restrict__ W1,
    const float* __restrict__ b1, const float* __restrict__ W2,
    const float* __restrict__ b2, float* __restrict__ out, int n) {
  __shared__ float Ws[ED * 64];
  for (int j = threadIdx.x; j < ED * 64; j += 256) Ws[j] = W1[j];
  __syncthreads();
  int node = blockIdx.x * 4 + (threadIdx.x >> 6);
  int t = threadIdx.x & 63;
  if (node >= n) return;
  const float* hr = h + (size_t)node * ED;
  float acc = b1[t];
  #pragma unroll 8
  for (int k = 0; k < ED; ++k) acc += hr[k] * Ws[k * 64 + t];
  float u = tanhf(acc) * W2[t];
  #pragma unroll
  for (int off = 32; off > 0; off >>= 1) u += __shfl_down(u, off, 64);
  if (t == 0) out[node] = u + b2[0];
}

// ---------------- host ----------------
extern "C" void kernel_launch(void* const* d_in, const int* in_sizes, int n_in,
                              void* d_out, int out_size, void* d_ws, size_t ws_size,
                              hipStream_t stream) {
  const float* node_feature = (const float*)d_in[0];
  const int*   edge_index   = (const int*)d_in[1];
  const float* enc_W  = (const float*)d_in[3];
  const float* enc_b  = (const float*)d_in[4];
  const float* gate_W = (const float*)d_in[5];
  const float* gate_b = (const float*)d_in[6];
  const float* att_W  = (const float*)d_in[7];
  const float* att_b  = (const float*)d_in[8];
  const float* msg_W  = (const float*)d_in[9];
  const float* msg_b  = (const float*)d_in[10];
  const float* upd_W  = (const float*)d_in[11];
  const float* upd_b  = (const float*)d_in[12];
  const float* dec1_W = (const float*)d_in[13];
  const float* dec1_b = (const float*)d_in[14];
  const float* dec2_W = (const float*)d_in[15];
  const float* dec2_b = (const float*)d_in[16];

  const int n = in_sizes[0] / 2;   // 50000
  const int E = in_sizes[1] / 2;   // 800000
  const int* src = edge_index;
  const int* dst = edge_index + E;

  char* ws = (char*)d_ws;
  size_t off = 0;
  auto alloc = [&](size_t bytes) -> void* {
    void* p = ws + off;
    off += (bytes + 255) & ~(size_t)255;
    return p;
  };
  float* hA   = (float*)alloc((size_t)n * ED * 4);
  float* hB   = (float*)alloc((size_t)n * ED * 4);
  char*  P    = (char*)alloc((size_t)n * PSTRIDE);
  float* aggr = (float*)alloc((size_t)n * ED * 4);
  int* deg    = (int*)alloc((size_t)n * 4);
  int* offs   = (int*)alloc((size_t)(n + 1) * 4);
  int* cursor = (int*)alloc((size_t)n * 4);
  int* ssrc   = (int*)alloc((size_t)E * 4);

  // CSR build (once per call)
  hipMemsetAsync(deg, 0, (size_t)n * 4, stream);
  count_deg_kernel<<<(E + 255) / 256, 256, 0, stream>>>(dst, deg, E);
  scan_kernel<<<1, 1024, 0, stream>>>(deg, offs, cursor, n);
  scatter_kernel<<<(E + 255) / 256, 256, 0, stream>>>(src, dst, cursor, ssrc, E);

  // encoder
  encoder_kernel<<<((size_t)n * ED + 255) / 256, 256, 0, stream>>>(
      node_feature, enc_W, enc_b, hA, n);

  float* h = hA;
  float* scratch = hB;
  const int gemm_grid = (n + 31) / 32;

  for (int l = 0; l < 3; ++l) {
    const float* mW = msg_W + (size_t)l * ED * ED;
    const float* mb = msg_b + (size_t)l * ED;
    const float* gW = gate_W + (size_t)l * ED * ED;
    const float* gb = gate_b + (size_t)l * ED;
    const float* aW = att_W + (size_t)l * ED * ED;
    const float* ab = att_b + (size_t)l * ED;
    const float* uW = upd_W + (size_t)l * 2 * ED * ED;
    const float* ub = upd_b + (size_t)l * ED;

    // fused: M (LDS) -> G fp32 + V bf16 packed into P
    gemm_mgv_kernel<<<gemm_grid, 256, 0, stream>>>(h, mW, mb, gW, gb, aW, ab, P, n);
    // single-pass online segment softmax + weighted sum
    edge_aggr2_kernel<<<n, 128, 0, stream>>>(offs, ssrc, P, aggr, n);
    // h_new = tanh([h, aggr] @ upd_W + upd_b)
    gemm_node_kernel<2><<<gemm_grid, 256, 0, stream>>>(h, aggr, uW, ub, scratch, n, 1);
    // swap
    float* tmp = h; h = scratch; scratch = tmp;
  }

  decoder_kernel<<<(n + 3) / 4, 256, 0, stream>>>(
      h, dec1_W, dec1_b, dec2_W, dec2_b, (float*)d_out, n);
}

// Round 3
// 763.950 us; speedup vs baseline: 1.4881x; 1.2711x over previous
//
#include <hip/hip_runtime.h>
#include <math.h>

#define ED 128
// packed per-node row: 128 f16 G + 128 f16 V = 512B = 256 f16
#define PROW 256

typedef _Float16 f16;
typedef _Float16 half8 __attribute__((ext_vector_type(8)));
typedef float f32x4 __attribute__((ext_vector_type(4)));

// ---------------- encoder: h = tanh(x @ enc_W + enc_b) -> f16 ----------------
__global__ __launch_bounds__(256) void encoder_kernel(
    const float* __restrict__ x, const float* __restrict__ W,
    const float* __restrict__ b, f16* __restrict__ h, int n) {
  int idx = blockIdx.x * blockDim.x + threadIdx.x;
  if (idx >= n * ED) return;
  int i = idx >> 7, c = idx & 127;
  float v = x[i * 2 + 0] * W[c] + x[i * 2 + 1] * W[ED + c] + b[c];
  h[idx] = (f16)tanhf(v);
}

// ---------------- weight transpose+cast: dst[l][c][k] = (f16)src[l][k][c] ----
__global__ __launch_bounds__(256) void transpose_w_kernel(
    const float* __restrict__ src, f16* __restrict__ dst, int K, int total) {
  int idx = blockIdx.x * 256 + threadIdx.x;
  if (idx >= total) return;
  int k = idx % K;
  int c = (idx / K) & 127;
  int l = idx / (K * 128);
  dst[idx] = (f16)src[(size_t)l * K * 128 + (size_t)k * 128 + c];
}

// ---------------- CSR build ----------------
__global__ __launch_bounds__(256) void count_deg_kernel(
    const int* __restrict__ dst, int* __restrict__ deg, int E) {
  int e = blockIdx.x * blockDim.x + threadIdx.x;
  if (e < E) atomicAdd(&deg[dst[e]], 1);
}

__global__ __launch_bounds__(1024) void scan_kernel(
    const int* __restrict__ deg, int* __restrict__ offs,
    int* __restrict__ cursor, int n) {
  __shared__ int wsum[16];
  __shared__ int carry_s;
  const int tid = threadIdx.x;
  const int lane = tid & 63;
  const int wid = tid >> 6;
  if (tid == 0) carry_s = 0;
  __syncthreads();
  for (int base = 0; base < n; base += 1024) {
    const int i = base + tid;
    const int v = (i < n) ? deg[i] : 0;
    int x = v;
    #pragma unroll
    for (int d = 1; d < 64; d <<= 1) {
      int t = __shfl_up(x, d, 64);
      if (lane >= d) x += t;
    }
    if (lane == 63) wsum[wid] = x;
    __syncthreads();
    int wbase = 0, total = 0;
    #pragma unroll
    for (int w = 0; w < 16; ++w) {
      int s = wsum[w];
      if (w < wid) wbase += s;
      total += s;
    }
    const int carry = carry_s;
    if (i < n) {
      const int excl = carry + wbase + x - v;
      offs[i] = excl;
      cursor[i] = excl;
    }
    __syncthreads();
    if (tid == 0) carry_s = carry + total;
    __syncthreads();
  }
  if (tid == 0) offs[n] = carry_s;
}

__global__ __launch_bounds__(256) void scatter_kernel(
    const int* __restrict__ src, const int* __restrict__ dst,
    int* __restrict__ cursor, int* __restrict__ ssrc, int E) {
  int e = blockIdx.x * blockDim.x + threadIdx.x;
  if (e < E) {
    int d = dst[e];
    int pos = atomicAdd(&cursor[d], 1);
    ssrc[pos] = src[e];
  }
}

// ---------------- fused MGV (MFMA f16) ----------------
// per block: 64 rows, 4 waves (16 rows each). All GEMMs K=128, N=128.
// M = tanh(h@mW+mb) kept in swizzled LDS; G = M@gW+gb -> P[0:128];
// V = tanh(M@aW+ab) -> P[128:256].
__global__ __launch_bounds__(256) void gemm_mgv_kernel(
    const f16* __restrict__ h,
    const f16* __restrict__ mWt, const float* __restrict__ mb,
    const f16* __restrict__ gWt, const float* __restrict__ gb,
    const f16* __restrict__ aWt, const float* __restrict__ ab,
    f16* __restrict__ P, int n) {
  __shared__ f16 Ms[64 * 128];
  char* Msb = reinterpret_cast<char*>(Ms);
  const int tid = threadIdx.x;
  const int w = tid >> 6, lane = tid & 63;
  const int lr = lane & 15;   // row-in-tile (A/D col for B)
  const int lg = lane >> 4;   // k-group 0..3
  const int r0 = blockIdx.x * 64 + w * 16;

  // ---- A-frags of h (16 rows x 128 k per wave, direct from global) ----
  half8 a[4];
  {
    int rr = r0 + lr;
    if (rr >= n) rr = n - 1;
    const f16* ap = h + (size_t)rr * ED + lg * 8;
    #pragma unroll
    for (int kt = 0; kt < 4; ++kt)
      a[kt] = *reinterpret_cast<const half8*>(ap + kt * 32);
  }

  // ---- phase 1: M tile -> swizzled LDS ----
  #pragma unroll
  for (int t = 0; t < 8; ++t) {
    f32x4 acc = {0.f, 0.f, 0.f, 0.f};
    const f16* bp = mWt + (size_t)(t * 16 + lr) * ED + lg * 8;
    #pragma unroll
    for (int kt = 0; kt < 4; ++kt) {
      half8 b = *reinterpret_cast<const half8*>(bp + kt * 32);
      acc = __builtin_amdgcn_mfma_f32_16x16x32_f16(a[kt], b, acc, 0, 0, 0);
    }
    int col = t * 16 + lr;
    float bias = mb[col];
    #pragma unroll
    for (int j = 0; j < 4; ++j) {
      int lrow = w * 16 + lg * 4 + j;
      int byte = lrow * 256 + (((col * 2) ^ ((lrow & 7) << 4)));
      *reinterpret_cast<f16*>(Msb + byte) = (f16)tanhf(acc[j] + bias);
    }
  }
  __syncthreads();

  // ---- A-frags of M from LDS (swizzled b128 reads, conflict-light) ----
  half8 ma[4];
  {
    int lrow = w * 16 + lr;
    #pragma unroll
    for (int kt = 0; kt < 4; ++kt) {
      int byte = lrow * 256 + ((lg * 16 + kt * 64) ^ ((lrow & 7) << 4));
      ma[kt] = *reinterpret_cast<const half8*>(Msb + byte);
    }
  }

  // ---- phase 2: G = M@gW + gb (f16 store) ----
  #pragma unroll
  for (int t = 0; t < 8; ++t) {
    f32x4 acc = {0.f, 0.f, 0.f, 0.f};
    const f16* bp = gWt + (size_t)(t * 16 + lr) * ED + lg * 8;
    #pragma unroll
    for (int kt = 0; kt < 4; ++kt) {
      half8 b = *reinterpret_cast<const half8*>(bp + kt * 32);
      acc = __builtin_amdgcn_mfma_f32_16x16x32_f16(ma[kt], b, acc, 0, 0, 0);
    }
    int col = t * 16 + lr;
    float bias = gb[col];
    #pragma unroll
    for (int j = 0; j < 4; ++j) {
      int grow = r0 + lg * 4 + j;
      if (grow < n) P[(size_t)grow * PROW + col] = (f16)(acc[j] + bias);
    }
  }

  // ---- phase 3: V = tanh(M@aW + ab) (f16 store) ----
  #pragma unroll
  for (int t = 0; t < 8; ++t) {
    f32x4 acc = {0.f, 0.f, 0.f, 0.f};
    const f16* bp = aWt + (size_t)(t * 16 + lr) * ED + lg * 8;
    #pragma unroll
    for (int kt = 0; kt < 4; ++kt) {
      half8 b = *reinterpret_cast<const half8*>(bp + kt * 32);
      acc = __builtin_amdgcn_mfma_f32_16x16x32_f16(ma[kt], b, acc, 0, 0, 0);
    }
    int col = t * 16 + lr;
    float bias = ab[col];
    #pragma unroll
    for (int j = 0; j < 4; ++j) {
      int grow = r0 + lg * 4 + j;
      if (grow < n) P[(size_t)grow * PROW + 128 + col] = (f16)tanhf(acc[j] + bias);
    }
  }
}

// ---------------- upd GEMM (MFMA f16): h_new = tanh([h,aggr]@uW + ub) --------
// uWt: [128 cols][256 k] f16 (k 0..127 = h part, 128..255 = aggr part)
__global__ __launch_bounds__(256) void gemm_upd_kernel(
    const f16* __restrict__ h, const f16* __restrict__ ag,
    const f16* __restrict__ uWt, const float* __restrict__ ub,
    f16* __restrict__ out, int n) {
  const int tid = threadIdx.x;
  const int w = tid >> 6, lane = tid & 63;
  const int lr = lane & 15;
  const int lg = lane >> 4;
  const int r0 = blockIdx.x * 64 + w * 16;

  half8 ah[4], aa[4];
  {
    int rr = r0 + lr;
    if (rr >= n) rr = n - 1;
    const f16* ap = h + (size_t)rr * ED + lg * 8;
    const f16* bp = ag + (size_t)rr * ED + lg * 8;
    #pragma unroll
    for (int kt = 0; kt < 4; ++kt) {
      ah[kt] = *reinterpret_cast<const half8*>(ap + kt * 32);
      aa[kt] = *reinterpret_cast<const half8*>(bp + kt * 32);
    }
  }

  #pragma unroll
  for (int t = 0; t < 8; ++t) {
    f32x4 acc = {0.f, 0.f, 0.f, 0.f};
    const f16* bp = uWt + (size_t)(t * 16 + lr) * 256 + lg * 8;
    #pragma unroll
    for (int kt = 0; kt < 4; ++kt) {
      half8 b = *reinterpret_cast<const half8*>(bp + kt * 32);
      acc = __builtin_amdgcn_mfma_f32_16x16x32_f16(ah[kt], b, acc, 0, 0, 0);
    }
    #pragma unroll
    for (int kt = 0; kt < 4; ++kt) {
      half8 b = *reinterpret_cast<const half8*>(bp + 128 + kt * 32);
      acc = __builtin_amdgcn_mfma_f32_16x16x32_f16(aa[kt], b, acc, 0, 0, 0);
    }
    int col = t * 16 + lr;
    float bias = ub[col];
    #pragma unroll
    for (int j = 0; j < 4; ++j) {
      int grow = r0 + lg * 4 + j;
      if (grow < n) out[(size_t)grow * ED + col] = (f16)tanhf(acc[j] + bias);
    }
  }
}

// ---------------- edge aggregation: single-pass online segment softmax -------
__global__ __launch_bounds__(128) void edge_aggr_kernel(
    const int* __restrict__ offs, const int* __restrict__ ssrc,
    const f16* __restrict__ P, f16* __restrict__ aggr, int n) {
  int i = blockIdx.x;
  if (i >= n) return;
  int c = threadIdx.x;
  int s0 = offs[i], s1 = offs[i + 1];

  float m = -INFINITY, s = 0.0f, a = 0.0f;
  for (int e = s0; e < s1; ++e) {
    int sn = ssrc[e];
    const f16* row = P + (size_t)sn * PROW;
    float g = (float)row[c];
    float v = (float)row[128 + c];
    float nm = fmaxf(m, g);
    float f = __expf(m - nm);
    float wgt = __expf(g - nm);
    s = s * f + wgt;
    a = a * f + wgt * v;
    m = nm;
  }
  aggr[(size_t)i * ED + c] = (f16)(a / (s + 1e-16f));
}

// ---------------- decoder: out = tanh(h @ W1 + b1) @ W2 + b2 ----------------
__global__ __launch_bounds__(256) void decoder_kernel(
    const f16* __restrict__ h, const float* __restrict__ W1,
    const float* __restrict__ b1, const float* __restrict__ W2,
    const float* __restrict__ b2, float* __restrict__ out, int n) {
  __shared__ float Ws[ED * 64];
  for (int j = threadIdx.x; j < ED * 64; j += 256) Ws[j] = W1[j];
  __syncthreads();
  int node = blockIdx.x * 4 + (threadIdx.x >> 6);
  int t = threadIdx.x & 63;
  if (node >= n) return;
  const f16* hr = h + (size_t)node * ED;
  float acc = b1[t];
  #pragma unroll 8
  for (int k = 0; k < ED; ++k) acc += (float)hr[k] * Ws[k * 64 + t];
  float u = tanhf(acc) * W2[t];
  #pragma unroll
  for (int off = 32; off > 0; off >>= 1) u += __shfl_down(u, off, 64);
  if (t == 0) out[node] = u + b2[0];
}

// ---------------- host ----------------
extern "C" void kernel_launch(void* const* d_in, const int* in_sizes, int n_in,
                              void* d_out, int out_size, void* d_ws, size_t ws_size,
                              hipStream_t stream) {
  const float* node_feature = (const float*)d_in[0];
  const int*   edge_index   = (const int*)d_in[1];
  const float* enc_W  = (const float*)d_in[3];
  const float* enc_b  = (const float*)d_in[4];
  const float* gate_W = (const float*)d_in[5];
  const float* gate_b = (const float*)d_in[6];
  const float* att_W  = (const float*)d_in[7];
  const float* att_b  = (const float*)d_in[8];
  const float* msg_W  = (const float*)d_in[9];
  const float* msg_b  = (const float*)d_in[10];
  const float* upd_W  = (const float*)d_in[11];
  const float* upd_b  = (const float*)d_in[12];
  const float* dec1_W = (const float*)d_in[13];
  const float* dec1_b = (const float*)d_in[14];
  const float* dec2_W = (const float*)d_in[15];
  const float* dec2_b = (const float*)d_in[16];

  const int n = in_sizes[0] / 2;   // 50000
  const int E = in_sizes[1] / 2;   // 800000
  const int* src = edge_index;
  const int* dst = edge_index + E;

  char* ws = (char*)d_ws;
  size_t off = 0;
  auto alloc = [&](size_t bytes) -> void* {
    void* p = ws + off;
    off += (bytes + 255) & ~(size_t)255;
    return p;
  };
  f16* hA   = (f16*)alloc((size_t)n * ED * 2);
  f16* hB   = (f16*)alloc((size_t)n * ED * 2);
  f16* P    = (f16*)alloc((size_t)n * PROW * 2);
  f16* aggr = (f16*)alloc((size_t)n * ED * 2);
  int* deg    = (int*)alloc((size_t)n * 4);
  int* offs   = (int*)alloc((size_t)(n + 1) * 4);
  int* cursor = (int*)alloc((size_t)n * 4);
  int* ssrc   = (int*)alloc((size_t)E * 4);
  f16* msgT = (f16*)alloc((size_t)3 * ED * ED * 2);
  f16* gateT = (f16*)alloc((size_t)3 * ED * ED * 2);
  f16* attT = (f16*)alloc((size_t)3 * ED * ED * 2);
  f16* updT = (f16*)alloc((size_t)3 * ED * 2 * ED * 2);

  // weight transpose+cast to f16 (once per call)
  {
    int tot = 3 * ED * ED;
    transpose_w_kernel<<<(tot + 255) / 256, 256, 0, stream>>>(msg_W, msgT, ED, tot);
    transpose_w_kernel<<<(tot + 255) / 256, 256, 0, stream>>>(gate_W, gateT, ED, tot);
    transpose_w_kernel<<<(tot + 255) / 256, 256, 0, stream>>>(att_W, attT, ED, tot);
    int tot2 = 3 * 2 * ED * ED;
    transpose_w_kernel<<<(tot2 + 255) / 256, 256, 0, stream>>>(upd_W, updT, 2 * ED, tot2);
  }

  // CSR build (once per call)
  hipMemsetAsync(deg, 0, (size_t)n * 4, stream);
  count_deg_kernel<<<(E + 255) / 256, 256, 0, stream>>>(dst, deg, E);
  scan_kernel<<<1, 1024, 0, stream>>>(deg, offs, cursor, n);
  scatter_kernel<<<(E + 255) / 256, 256, 0, stream>>>(src, dst, cursor, ssrc, E);

  // encoder
  encoder_kernel<<<((size_t)n * ED + 255) / 256, 256, 0, stream>>>(
      node_feature, enc_W, enc_b, hA, n);

  f16* h = hA;
  f16* scratch = hB;
  const int gemm_grid = (n + 63) / 64;

  for (int l = 0; l < 3; ++l) {
    gemm_mgv_kernel<<<gemm_grid, 256, 0, stream>>>(
        h,
        msgT + (size_t)l * ED * ED, msg_b + (size_t)l * ED,
        gateT + (size_t)l * ED * ED, gate_b + (size_t)l * ED,
        attT + (size_t)l * ED * ED, att_b + (size_t)l * ED,
        P, n);
    edge_aggr_kernel<<<n, 128, 0, stream>>>(offs, ssrc, P, aggr, n);
    gemm_upd_kernel<<<gemm_grid, 256, 0, stream>>>(
        h, aggr, updT + (size_t)l * 2 * ED * ED, upd_b + (size_t)l * ED, scratch, n);
    f16* tmp = h; h = scratch; scratch = tmp;
  }

  decoder_kernel<<<(n + 3) / 4, 256, 0, stream>>>(
      h, dec1_W, dec1_b, dec2_W, dec2_b, (float*)d_out, n);
}

// Round 4
// 579.948 us; speedup vs baseline: 1.9602x; 1.3173x over previous
//
#include <hip/hip_runtime.h>
#include <math.h>

#define ED 128
// packed per-node row: 128 f16 w=exp(gate) + 128 f16 wv=w*v  (512 B)
#define PROW 256

typedef _Float16 f16;
typedef _Float16 half8 __attribute__((ext_vector_type(8)));
typedef _Float16 half4 __attribute__((ext_vector_type(4)));
typedef float f32x4 __attribute__((ext_vector_type(4)));

// ---------------- encoder: h = tanh(x @ enc_W + enc_b) -> f16 ----------------
__global__ __launch_bounds__(256) void encoder_kernel(
    const float* __restrict__ x, const float* __restrict__ W,
    const float* __restrict__ b, f16* __restrict__ h, int n) {
  int idx = blockIdx.x * blockDim.x + threadIdx.x;
  if (idx >= n * ED) return;
  int i = idx >> 7, c = idx & 127;
  float v = x[i * 2 + 0] * W[c] + x[i * 2 + 1] * W[ED + c] + b[c];
  h[idx] = (f16)tanhf(v);
}

// ---------------- weight transpose+cast ----------------
// generic: for 'mats' matrices of [K][C] fp32, dst[m][c][k] = (f16)src[m][k][c]
__global__ __launch_bounds__(256) void transpose_w_kernel(
    const float* __restrict__ src, f16* __restrict__ dst, int K, int C, int total) {
  int idx = blockIdx.x * 256 + threadIdx.x;
  if (idx >= total) return;
  int kc = K * C;
  int m = idx / kc;
  int rem = idx - m * kc;
  int c = rem / K;
  int k = rem - c * K;
  dst[idx] = (f16)src[(size_t)m * kc + (size_t)k * C + c];
}

// msg/gate/att: 3 arrays, each 3 mats of [128][128]
__global__ __launch_bounds__(256) void transpose3_kernel(
    const float* __restrict__ s0, const float* __restrict__ s1,
    const float* __restrict__ s2, f16* __restrict__ d0,
    f16* __restrict__ d1, f16* __restrict__ d2) {
  int idx = blockIdx.x * 256 + threadIdx.x;
  const int per = 3 * 128 * 128;
  int which = idx / per;
  if (which >= 3) return;
  int rem = idx - which * per;
  const float* s = (which == 0) ? s0 : (which == 1) ? s1 : s2;
  f16* d = (which == 0) ? d0 : (which == 1) ? d1 : d2;
  int m = rem >> 14;
  int r2 = rem & 16383;
  int c = r2 >> 7, k = r2 & 127;
  d[rem] = (f16)s[m * 16384 + k * 128 + c];
}

// ---------------- CSR build ----------------
__global__ __launch_bounds__(256) void count_deg_kernel(
    const int* __restrict__ dst, int* __restrict__ deg, int E) {
  int e = blockIdx.x * blockDim.x + threadIdx.x;
  if (e < E) atomicAdd(&deg[dst[e]], 1);
}

__global__ __launch_bounds__(1024) void scan_kernel(
    const int* __restrict__ deg, int* __restrict__ offs,
    int* __restrict__ cursor, int n) {
  __shared__ int wsum[16];
  __shared__ int carry_s;
  const int tid = threadIdx.x;
  const int lane = tid & 63;
  const int wid = tid >> 6;
  if (tid == 0) carry_s = 0;
  __syncthreads();
  for (int base = 0; base < n; base += 1024) {
    const int i = base + tid;
    const int v = (i < n) ? deg[i] : 0;
    int x = v;
    #pragma unroll
    for (int d = 1; d < 64; d <<= 1) {
      int t = __shfl_up(x, d, 64);
      if (lane >= d) x += t;
    }
    if (lane == 63) wsum[wid] = x;
    __syncthreads();
    int wbase = 0, total = 0;
    #pragma unroll
    for (int w = 0; w < 16; ++w) {
      int s = wsum[w];
      if (w < wid) wbase += s;
      total += s;
    }
    const int carry = carry_s;
    if (i < n) {
      const int excl = carry + wbase + x - v;
      offs[i] = excl;
      cursor[i] = excl;
    }
    __syncthreads();
    if (tid == 0) carry_s = carry + total;
    __syncthreads();
  }
  if (tid == 0) offs[n] = carry_s;
}

__global__ __launch_bounds__(256) void scatter_kernel(
    const int* __restrict__ src, const int* __restrict__ dst,
    int* __restrict__ cursor, int* __restrict__ ssrc, int E) {
  int e = blockIdx.x * blockDim.x + threadIdx.x;
  if (e < E) {
    int d = dst[e];
    int pos = atomicAdd(&cursor[d], 1);
    ssrc[pos] = src[e];
  }
}

// ---------------- MGV layer 0 (MFMA f16) ----------------
// M = tanh(h@mW+mb) in swizzled LDS; w = exp(M@gW+gb) -> P[0:128];
// wv = w * tanh(M@aW+ab) -> P[128:256].
__global__ __launch_bounds__(256) void gemm_mgv_kernel(
    const f16* __restrict__ h,
    const f16* __restrict__ mWt, const float* __restrict__ mb,
    const f16* __restrict__ gWt, const float* __restrict__ gb,
    const f16* __restrict__ aWt, const float* __restrict__ ab,
    f16* __restrict__ P, int n) {
  __shared__ f16 Ms[64 * 128];
  char* Msb = reinterpret_cast<char*>(Ms);
  const int tid = threadIdx.x;
  const int w = tid >> 6, lane = tid & 63;
  const int lr = lane & 15;
  const int lg = lane >> 4;
  const int r0 = blockIdx.x * 64 + w * 16;

  half8 a[4];
  {
    int rr = r0 + lr;
    if (rr >= n) rr = n - 1;
    const f16* ap = h + (size_t)rr * ED + lg * 8;
    #pragma unroll
    for (int kt = 0; kt < 4; ++kt)
      a[kt] = *reinterpret_cast<const half8*>(ap + kt * 32);
  }

  // phase 1: M tile -> swizzled LDS
  #pragma unroll
  for (int t = 0; t < 8; ++t) {
    f32x4 acc = {0.f, 0.f, 0.f, 0.f};
    const f16* bp = mWt + (size_t)(t * 16 + lr) * ED + lg * 8;
    #pragma unroll
    for (int kt = 0; kt < 4; ++kt) {
      half8 b = *reinterpret_cast<const half8*>(bp + kt * 32);
      acc = __builtin_amdgcn_mfma_f32_16x16x32_f16(a[kt], b, acc, 0, 0, 0);
    }
    int col = t * 16 + lr;
    float bias = mb[col];
    #pragma unroll
    for (int j = 0; j < 4; ++j) {
      int lrow = w * 16 + lg * 4 + j;
      int byte = lrow * 256 + (((col * 2) ^ ((lrow & 7) << 4)));
      *reinterpret_cast<f16*>(Msb + byte) = (f16)tanhf(acc[j] + bias);
    }
  }
  __syncthreads();

  half8 ma[4];
  {
    int lrow = w * 16 + lr;
    #pragma unroll
    for (int kt = 0; kt < 4; ++kt) {
      int byte = lrow * 256 + ((lg * 16 + kt * 64) ^ ((lrow & 7) << 4));
      ma[kt] = *reinterpret_cast<const half8*>(Msb + byte);
    }
  }

  // phase 2: w = exp(M@gW + gb)
  float wreg[8][4];
  #pragma unroll
  for (int t = 0; t < 8; ++t) {
    f32x4 acc = {0.f, 0.f, 0.f, 0.f};
    const f16* bp = gWt + (size_t)(t * 16 + lr) * ED + lg * 8;
    #pragma unroll
    for (int kt = 0; kt < 4; ++kt) {
      half8 b = *reinterpret_cast<const half8*>(bp + kt * 32);
      acc = __builtin_amdgcn_mfma_f32_16x16x32_f16(ma[kt], b, acc, 0, 0, 0);
    }
    int col = t * 16 + lr;
    float bias = gb[col];
    #pragma unroll
    for (int j = 0; j < 4; ++j) {
      float ww = fminf(__expf(acc[j] + bias), 60000.f);
      wreg[t][j] = ww;
      int grow = r0 + lg * 4 + j;
      if (grow < n) P[(size_t)grow * PROW + col] = (f16)ww;
    }
  }

  // phase 3: wv = w * tanh(M@aW + ab)
  #pragma unroll
  for (int t = 0; t < 8; ++t) {
    f32x4 acc = {0.f, 0.f, 0.f, 0.f};
    const f16* bp = aWt + (size_t)(t * 16 + lr) * ED + lg * 8;
    #pragma unroll
    for (int kt = 0; kt < 4; ++kt) {
      half8 b = *reinterpret_cast<const half8*>(bp + kt * 32);
      acc = __builtin_amdgcn_mfma_f32_16x16x32_f16(ma[kt], b, acc, 0, 0, 0);
    }
    int col = t * 16 + lr;
    float bias = ab[col];
    #pragma unroll
    for (int j = 0; j < 4; ++j) {
      int grow = r0 + lg * 4 + j;
      if (grow < n)
        P[(size_t)grow * PROW + 128 + col] = (f16)(wreg[t][j] * tanhf(acc[j] + bias));
    }
  }
}

// ---------------- fused upd + MGV (layers 1,2) ----------------
// h_new = tanh([h,aggr]@uW+ub) -> global + swizzled LDS;
// then M/G/V phases on h_new producing P.
__global__ __launch_bounds__(256) void updmgv_kernel(
    const f16* __restrict__ h, const f16* __restrict__ ag,
    const f16* __restrict__ uWt, const float* __restrict__ ub,
    const f16* __restrict__ mWt, const float* __restrict__ mb,
    const f16* __restrict__ gWt, const float* __restrict__ gb,
    const f16* __restrict__ aWt, const float* __restrict__ ab,
    f16* __restrict__ hout, f16* __restrict__ P, int n) {
  __shared__ f16 Hs[64 * 128];
  __shared__ f16 Ms[64 * 128];
  char* Hsb = reinterpret_cast<char*>(Hs);
  char* Msb = reinterpret_cast<char*>(Ms);
  const int tid = threadIdx.x;
  const int w = tid >> 6, lane = tid & 63;
  const int lr = lane & 15;
  const int lg = lane >> 4;
  const int r0 = blockIdx.x * 64 + w * 16;

  // A-frags of h, aggr
  half8 ah[4], aa[4];
  {
    int rr = r0 + lr;
    if (rr >= n) rr = n - 1;
    const f16* ap = h + (size_t)rr * ED + lg * 8;
    const f16* bp = ag + (size_t)rr * ED + lg * 8;
    #pragma unroll
    for (int kt = 0; kt < 4; ++kt) {
      ah[kt] = *reinterpret_cast<const half8*>(ap + kt * 32);
      aa[kt] = *reinterpret_cast<const half8*>(bp + kt * 32);
    }
  }

  // phase U: h_new -> global + swizzled LDS
  #pragma unroll
  for (int t = 0; t < 8; ++t) {
    f32x4 acc = {0.f, 0.f, 0.f, 0.f};
    const f16* bp = uWt + (size_t)(t * 16 + lr) * 256 + lg * 8;
    #pragma unroll
    for (int kt = 0; kt < 4; ++kt) {
      half8 b = *reinterpret_cast<const half8*>(bp + kt * 32);
      acc = __builtin_amdgcn_mfma_f32_16x16x32_f16(ah[kt], b, acc, 0, 0, 0);
    }
    #pragma unroll
    for (int kt = 0; kt < 4; ++kt) {
      half8 b = *reinterpret_cast<const half8*>(bp + 128 + kt * 32);
      acc = __builtin_amdgcn_mfma_f32_16x16x32_f16(aa[kt], b, acc, 0, 0, 0);
    }
    int col = t * 16 + lr;
    float bias = ub[col];
    #pragma unroll
    for (int j = 0; j < 4; ++j) {
      f16 hv = (f16)tanhf(acc[j] + bias);
      int lrow = w * 16 + lg * 4 + j;
      int byte = lrow * 256 + (((col * 2) ^ ((lrow & 7) << 4)));
      *reinterpret_cast<f16*>(Hsb + byte) = hv;
      int grow = r0 + lg * 4 + j;
      if (grow < n) hout[(size_t)grow * ED + col] = hv;
    }
  }
  __syncthreads();

  // A-frags of h_new from LDS
  half8 ha[4];
  {
    int lrow = w * 16 + lr;
    #pragma unroll
    for (int kt = 0; kt < 4; ++kt) {
      int byte = lrow * 256 + ((lg * 16 + kt * 64) ^ ((lrow & 7) << 4));
      ha[kt] = *reinterpret_cast<const half8*>(Hsb + byte);
    }
  }

  // phase M: M tile -> Ms
  #pragma unroll
  for (int t = 0; t < 8; ++t) {
    f32x4 acc = {0.f, 0.f, 0.f, 0.f};
    const f16* bp = mWt + (size_t)(t * 16 + lr) * ED + lg * 8;
    #pragma unroll
    for (int kt = 0; kt < 4; ++kt) {
      half8 b = *reinterpret_cast<const half8*>(bp + kt * 32);
      acc = __builtin_amdgcn_mfma_f32_16x16x32_f16(ha[kt], b, acc, 0, 0, 0);
    }
    int col = t * 16 + lr;
    float bias = mb[col];
    #pragma unroll
    for (int j = 0; j < 4; ++j) {
      int lrow = w * 16 + lg * 4 + j;
      int byte = lrow * 256 + (((col * 2) ^ ((lrow & 7) << 4)));
      *reinterpret_cast<f16*>(Msb + byte) = (f16)tanhf(acc[j] + bias);
    }
  }
  __syncthreads();

  half8 ma[4];
  {
    int lrow = w * 16 + lr;
    #pragma unroll
    for (int kt = 0; kt < 4; ++kt) {
      int byte = lrow * 256 + ((lg * 16 + kt * 64) ^ ((lrow & 7) << 4));
      ma[kt] = *reinterpret_cast<const half8*>(Msb + byte);
    }
  }

  // phase G: w = exp(M@gW+gb)
  float wreg[8][4];
  #pragma unroll
  for (int t = 0; t < 8; ++t) {
    f32x4 acc = {0.f, 0.f, 0.f, 0.f};
    const f16* bp = gWt + (size_t)(t * 16 + lr) * ED + lg * 8;
    #pragma unroll
    for (int kt = 0; kt < 4; ++kt) {
      half8 b = *reinterpret_cast<const half8*>(bp + kt * 32);
      acc = __builtin_amdgcn_mfma_f32_16x16x32_f16(ma[kt], b, acc, 0, 0, 0);
    }
    int col = t * 16 + lr;
    float bias = gb[col];
    #pragma unroll
    for (int j = 0; j < 4; ++j) {
      float ww = fminf(__expf(acc[j] + bias), 60000.f);
      wreg[t][j] = ww;
      int grow = r0 + lg * 4 + j;
      if (grow < n) P[(size_t)grow * PROW + col] = (f16)ww;
    }
  }

  // phase V: wv = w * tanh(M@aW+ab)
  #pragma unroll
  for (int t = 0; t < 8; ++t) {
    f32x4 acc = {0.f, 0.f, 0.f, 0.f};
    const f16* bp = aWt + (size_t)(t * 16 + lr) * ED + lg * 8;
    #pragma unroll
    for (int kt = 0; kt < 4; ++kt) {
      half8 b = *reinterpret_cast<const half8*>(bp + kt * 32);
      acc = __builtin_amdgcn_mfma_f32_16x16x32_f16(ma[kt], b, acc, 0, 0, 0);
    }
    int col = t * 16 + lr;
    float bias = ab[col];
    #pragma unroll
    for (int j = 0; j < 4; ++j) {
      int grow = r0 + lg * 4 + j;
      if (grow < n)
        P[(size_t)grow * PROW + 128 + col] = (f16)(wreg[t][j] * tanhf(acc[j] + bias));
    }
  }
}

// ---------------- fused upd + decoder (layer 2 end) ----------------
__global__ __launch_bounds__(256) void upddec_kernel(
    const f16* __restrict__ h, const f16* __restrict__ ag,
    const f16* __restrict__ uWt, const float* __restrict__ ub,
    const f16* __restrict__ d1Wt, const float* __restrict__ d1b,
    const float* __restrict__ d2W, const float* __restrict__ d2b,
    float* __restrict__ out, int n) {
  __shared__ f16 Hs[64 * 128];
  char* Hsb = reinterpret_cast<char*>(Hs);
  const int tid = threadIdx.x;
  const int w = tid >> 6, lane = tid & 63;
  const int lr = lane & 15;
  const int lg = lane >> 4;
  const int r0 = blockIdx.x * 64 + w * 16;

  half8 ah[4], aa[4];
  {
    int rr = r0 + lr;
    if (rr >= n) rr = n - 1;
    const f16* ap = h + (size_t)rr * ED + lg * 8;
    const f16* bp = ag + (size_t)rr * ED + lg * 8;
    #pragma unroll
    for (int kt = 0; kt < 4; ++kt) {
      ah[kt] = *reinterpret_cast<const half8*>(ap + kt * 32);
      aa[kt] = *reinterpret_cast<const half8*>(bp + kt * 32);
    }
  }

  // h3 tile -> swizzled LDS only
  #pragma unroll
  for (int t = 0; t < 8; ++t) {
    f32x4 acc = {0.f, 0.f, 0.f, 0.f};
    const f16* bp = uWt + (size_t)(t * 16 + lr) * 256 + lg * 8;
    #pragma unroll
    for (int kt = 0; kt < 4; ++kt) {
      half8 b = *reinterpret_cast<const half8*>(bp + kt * 32);
      acc = __builtin_amdgcn_mfma_f32_16x16x32_f16(ah[kt], b, acc, 0, 0, 0);
    }
    #pragma unroll
    for (int kt = 0; kt < 4; ++kt) {
      half8 b = *reinterpret_cast<const half8*>(bp + 128 + kt * 32);
      acc = __builtin_amdgcn_mfma_f32_16x16x32_f16(aa[kt], b, acc, 0, 0, 0);
    }
    int col = t * 16 + lr;
    float bias = ub[col];
    #pragma unroll
    for (int j = 0; j < 4; ++j) {
      int lrow = w * 16 + lg * 4 + j;
      int byte = lrow * 256 + (((col * 2) ^ ((lrow & 7) << 4)));
      *reinterpret_cast<f16*>(Hsb + byte) = (f16)tanhf(acc[j] + bias);
    }
  }
  __syncthreads();

  half8 ha[4];
  {
    int lrow = w * 16 + lr;
    #pragma unroll
    for (int kt = 0; kt < 4; ++kt) {
      int byte = lrow * 256 + ((lg * 16 + kt * 64) ^ ((lrow & 7) << 4));
      ha[kt] = *reinterpret_cast<const half8*>(Hsb + byte);
    }
  }

  // decoder: y = tanh(h3 @ d1W + d1b); out = y @ d2W + d2b
  float rowsum[4] = {0.f, 0.f, 0.f, 0.f};
  #pragma unroll
  for (int t = 0; t < 4; ++t) {
    f32x4 acc = {0.f, 0.f, 0.f, 0.f};
    const f16* bp = d1Wt + (size_t)(t * 16 + lr) * ED + lg * 8;
    #pragma unroll
    for (int kt = 0; kt < 4; ++kt) {
      half8 b = *reinterpret_cast<const half8*>(bp + kt * 32);
      acc = __builtin_amdgcn_mfma_f32_16x16x32_f16(ha[kt], b, acc, 0, 0, 0);
    }
    int col = t * 16 + lr;
    float b1 = d1b[col], w2 = d2W[col];
    #pragma unroll
    for (int j = 0; j < 4; ++j) rowsum[j] += tanhf(acc[j] + b1) * w2;
  }
  // reduce across the 16 lr lanes (lane bits 0-3)
  #pragma unroll
  for (int d = 1; d < 16; d <<= 1) {
    #pragma unroll
    for (int j = 0; j < 4; ++j) rowsum[j] += __shfl_xor(rowsum[j], d, 64);
  }
  if (lr == 0) {
    #pragma unroll
    for (int j = 0; j < 4; ++j) {
      int grow = r0 + lg * 4 + j;
      if (grow < n) out[grow] = rowsum[j] + d2b[0];
    }
  }
}

// ---------------- edge aggregation: one wave per dst node, pure gather-sum ---
// lane l<32: s over channels 4l..4l+3 ; lane l>=32: wv over channels 4(l-32)..
__global__ __launch_bounds__(256) void edge_aggr_kernel(
    const int* __restrict__ offs, const int* __restrict__ ssrc,
    const f16* __restrict__ P, f16* __restrict__ aggr, int n) {
  int i = blockIdx.x * 4 + (threadIdx.x >> 6);
  if (i >= n) return;
  int lane = threadIdx.x & 63;
  int s0 = offs[i], s1 = offs[i + 1];
  const char* Pb = reinterpret_cast<const char*>(P);

  float4 acc = {0.f, 0.f, 0.f, 0.f};
  #pragma unroll 4
  for (int e = s0; e < s1; ++e) {
    int sn = ssrc[e];
    half4 x = *reinterpret_cast<const half4*>(Pb + (size_t)sn * 512 + lane * 8);
    acc.x += (float)x.x;
    acc.y += (float)x.y;
    acc.z += (float)x.z;
    acc.w += (float)x.w;
  }
  // exchange halves: partner lane^32
  float px = __shfl(acc.x, lane ^ 32, 64);
  float py = __shfl(acc.y, lane ^ 32, 64);
  float pz = __shfl(acc.z, lane ^ 32, 64);
  float pw = __shfl(acc.w, lane ^ 32, 64);
  if (lane >= 32) {
    // acc = wv sums, p* = w sums
    half4 o;
    o.x = (f16)(acc.x / (px + 1e-16f));
    o.y = (f16)(acc.y / (py + 1e-16f));
    o.z = (f16)(acc.z / (pz + 1e-16f));
    o.w = (f16)(acc.w / (pw + 1e-16f));
    *reinterpret_cast<half4*>(
        reinterpret_cast<char*>(aggr) + (size_t)i * 256 + (size_t)(lane - 32) * 8) = o;
  }
}

// ---------------- host ----------------
extern "C" void kernel_launch(void* const* d_in, const int* in_sizes, int n_in,
                              void* d_out, int out_size, void* d_ws, size_t ws_size,
                              hipStream_t stream) {
  const float* node_feature = (const float*)d_in[0];
  const int*   edge_index   = (const int*)d_in[1];
  const float* enc_W  = (const float*)d_in[3];
  const float* enc_b  = (const float*)d_in[4];
  const float* gate_W = (const float*)d_in[5];
  const float* gate_b = (const float*)d_in[6];
  const float* att_W  = (const float*)d_in[7];
  const float* att_b  = (const float*)d_in[8];
  const float* msg_W  = (const float*)d_in[9];
  const float* msg_b  = (const float*)d_in[10];
  const float* upd_W  = (const float*)d_in[11];
  const float* upd_b  = (const float*)d_in[12];
  const float* dec1_W = (const float*)d_in[13];
  const float* dec1_b = (const float*)d_in[14];
  const float* dec2_W = (const float*)d_in[15];
  const float* dec2_b = (const float*)d_in[16];

  const int n = in_sizes[0] / 2;   // 50000
  const int E = in_sizes[1] / 2;   // 800000
  const int* src = edge_index;
  const int* dst = edge_index + E;

  char* ws = (char*)d_ws;
  size_t off = 0;
  auto alloc = [&](size_t bytes) -> void* {
    void* p = ws + off;
    off += (bytes + 255) & ~(size_t)255;
    return p;
  };
  f16* hA   = (f16*)alloc((size_t)n * ED * 2);
  f16* hB   = (f16*)alloc((size_t)n * ED * 2);
  f16* P    = (f16*)alloc((size_t)n * PROW * 2);
  f16* aggr = (f16*)alloc((size_t)n * ED * 2);
  int* deg    = (int*)alloc((size_t)n * 4);
  int* offs   = (int*)alloc((size_t)(n + 1) * 4);
  int* cursor = (int*)alloc((size_t)n * 4);
  int* ssrc   = (int*)alloc((size_t)E * 4);
  f16* msgT  = (f16*)alloc((size_t)3 * ED * ED * 2);
  f16* gateT = (f16*)alloc((size_t)3 * ED * ED * 2);
  f16* attT  = (f16*)alloc((size_t)3 * ED * ED * 2);
  f16* updT  = (f16*)alloc((size_t)3 * ED * 2 * ED * 2);
  f16* dec1T = (f16*)alloc((size_t)ED * 64 * 2);

  // weight prep (once per call)
  {
    int tot3 = 3 * 3 * ED * ED;
    transpose3_kernel<<<(tot3 + 255) / 256, 256, 0, stream>>>(
        msg_W, gate_W, att_W, msgT, gateT, attT);
    int totu = 3 * 2 * ED * ED;
    transpose_w_kernel<<<(totu + 255) / 256, 256, 0, stream>>>(
        upd_W, updT, 2 * ED, ED, totu);
    int totd = ED * 64;
    transpose_w_kernel<<<(totd + 255) / 256, 256, 0, stream>>>(
        dec1_W, dec1T, ED, 64, totd);
  }

  // CSR build (once per call)
  hipMemsetAsync(deg, 0, (size_t)n * 4, stream);
  count_deg_kernel<<<(E + 255) / 256, 256, 0, stream>>>(dst, deg, E);
  scan_kernel<<<1, 1024, 0, stream>>>(deg, offs, cursor, n);
  scatter_kernel<<<(E + 255) / 256, 256, 0, stream>>>(src, dst, cursor, ssrc, E);

  // encoder
  encoder_kernel<<<((size_t)n * ED + 255) / 256, 256, 0, stream>>>(
      node_feature, enc_W, enc_b, hA, n);

  const int gemm_grid = (n + 63) / 64;
  const int aggr_grid = (n + 3) / 4;

  // layer 0 MGV
  gemm_mgv_kernel<<<gemm_grid, 256, 0, stream>>>(
      hA, msgT, msg_b, gateT, gate_b, attT, att_b, P, n);
  edge_aggr_kernel<<<aggr_grid, 256, 0, stream>>>(offs, ssrc, P, aggr, n);

  // upd0 + MGV1
  updmgv_kernel<<<gemm_grid, 256, 0, stream>>>(
      hA, aggr, updT, upd_b,
      msgT + (size_t)1 * ED * ED, msg_b + ED,
      gateT + (size_t)1 * ED * ED, gate_b + ED,
      attT + (size_t)1 * ED * ED, att_b + ED,
      hB, P, n);
  edge_aggr_kernel<<<aggr_grid, 256, 0, stream>>>(offs, ssrc, P, aggr, n);

  // upd1 + MGV2
  updmgv_kernel<<<gemm_grid, 256, 0, stream>>>(
      hB, aggr, updT + (size_t)1 * 2 * ED * ED, upd_b + ED,
      msgT + (size_t)2 * ED * ED, msg_b + 2 * ED,
      gateT + (size_t)2 * ED * ED, gate_b + 2 * ED,
      attT + (size_t)2 * ED * ED, att_b + 2 * ED,
      hA, P, n);
  edge_aggr_kernel<<<aggr_grid, 256, 0, stream>>>(offs, ssrc, P, aggr, n);

  // upd2 + decoder
  upddec_kernel<<<gemm_grid, 256, 0, stream>>>(
      hA, aggr, updT + (size_t)2 * 2 * ED * ED, upd_b + 2 * ED,
      dec1T, dec1_b, dec2_W, dec2_b, (float*)d_out, n);
}

// Round 5
// 554.900 us; speedup vs baseline: 2.0487x; 1.0451x over previous
//
#include <hip/hip_runtime.h>
#include <math.h>

#define ED 128
// packed per-node row: 128 f16 w=exp(gate) + 128 f16 wv=w*v  (512 B)
#define PROW 256

typedef _Float16 f16;
typedef _Float16 half8 __attribute__((ext_vector_type(8)));
typedef _Float16 half4 __attribute__((ext_vector_type(4)));
typedef float f32x4 __attribute__((ext_vector_type(4)));

// ---------------- encoder: h = tanh(x @ enc_W + enc_b) -> f16 ----------------
__global__ __launch_bounds__(256) void encoder_kernel(
    const float* __restrict__ x, const float* __restrict__ W,
    const float* __restrict__ b, f16* __restrict__ h, int n) {
  int idx = blockIdx.x * blockDim.x + threadIdx.x;
  if (idx >= n * ED) return;
  int i = idx >> 7, c = idx & 127;
  float v = x[i * 2 + 0] * W[c] + x[i * 2 + 1] * W[ED + c] + b[c];
  h[idx] = (f16)tanhf(v);
}

// ---------------- weight transpose+cast ----------------
__global__ __launch_bounds__(256) void transpose_w_kernel(
    const float* __restrict__ src, f16* __restrict__ dst, int K, int C, int total) {
  int idx = blockIdx.x * 256 + threadIdx.x;
  if (idx >= total) return;
  int kc = K * C;
  int m = idx / kc;
  int rem = idx - m * kc;
  int c = rem / K;
  int k = rem - c * K;
  dst[idx] = (f16)src[(size_t)m * kc + (size_t)k * C + c];
}

__global__ __launch_bounds__(256) void transpose3_kernel(
    const float* __restrict__ s0, const float* __restrict__ s1,
    const float* __restrict__ s2, f16* __restrict__ d0,
    f16* __restrict__ d1, f16* __restrict__ d2) {
  int idx = blockIdx.x * 256 + threadIdx.x;
  const int per = 3 * 128 * 128;
  int which = idx / per;
  if (which >= 3) return;
  int rem = idx - which * per;
  const float* s = (which == 0) ? s0 : (which == 1) ? s1 : s2;
  f16* d = (which == 0) ? d0 : (which == 1) ? d1 : d2;
  int m = rem >> 14;
  int r2 = rem & 16383;
  int c = r2 >> 7, k = r2 & 127;
  d[rem] = (f16)s[m * 16384 + k * 128 + c];
}

// ---------------- CSR build ----------------
__global__ __launch_bounds__(256) void count_deg_kernel(
    const int* __restrict__ dst, int* __restrict__ deg, int E) {
  int e = blockIdx.x * blockDim.x + threadIdx.x;
  if (e < E) atomicAdd(&deg[dst[e]], 1);
}

__global__ __launch_bounds__(1024) void scan_kernel(
    const int* __restrict__ deg, int* __restrict__ offs,
    int* __restrict__ cursor, int n) {
  __shared__ int wsum[16];
  __shared__ int carry_s;
  const int tid = threadIdx.x;
  const int lane = tid & 63;
  const int wid = tid >> 6;
  if (tid == 0) carry_s = 0;
  __syncthreads();
  for (int base = 0; base < n; base += 1024) {
    const int i = base + tid;
    const int v = (i < n) ? deg[i] : 0;
    int x = v;
    #pragma unroll
    for (int d = 1; d < 64; d <<= 1) {
      int t = __shfl_up(x, d, 64);
      if (lane >= d) x += t;
    }
    if (lane == 63) wsum[wid] = x;
    __syncthreads();
    int wbase = 0, total = 0;
    #pragma unroll
    for (int w = 0; w < 16; ++w) {
      int s = wsum[w];
      if (w < wid) wbase += s;
      total += s;
    }
    const int carry = carry_s;
    if (i < n) {
      const int excl = carry + wbase + x - v;
      offs[i] = excl;
      cursor[i] = excl;
    }
    __syncthreads();
    if (tid == 0) carry_s = carry + total;
    __syncthreads();
  }
  if (tid == 0) offs[n] = carry_s;
}

__global__ __launch_bounds__(256) void scatter_kernel(
    const int* __restrict__ src, const int* __restrict__ dst,
    int* __restrict__ cursor, int* __restrict__ ssrc, int E) {
  int e = blockIdx.x * blockDim.x + threadIdx.x;
  if (e < E) {
    int d = dst[e];
    int pos = atomicAdd(&cursor[d], 1);
    ssrc[pos] = src[e];
  }
}

// ==================== GEMM kernels, col-split layout ====================
// block = 256 threads = 4 waves = 2 row-stripes (16 rows) x 2 col-halves (64).
// rs = wave>>1, ch = wave&1; rows r0 = blockIdx*32 + rs*16;
// wave's output cols = ch*64 + tt*16 + lr, tt in 0..3.

// ---------------- MGV layer 0 ----------------
__global__ __launch_bounds__(256) void gemm_mgv_kernel(
    const f16* __restrict__ h,
    const f16* __restrict__ mWt, const float* __restrict__ mb,
    const f16* __restrict__ gWt, const float* __restrict__ gb,
    const f16* __restrict__ aWt, const float* __restrict__ ab,
    f16* __restrict__ P, int n) {
  __shared__ f16 Ms[32 * 128];
  char* Msb = reinterpret_cast<char*>(Ms);
  const int tid = threadIdx.x;
  const int w = tid >> 6, lane = tid & 63;
  const int rs = w >> 1, ch = w & 1;
  const int lr = lane & 15;
  const int lg = lane >> 4;
  const int r0 = blockIdx.x * 32 + rs * 16;

  half8 a[4];
  {
    int rr = r0 + lr;
    if (rr >= n) rr = n - 1;
    const f16* ap = h + (size_t)rr * ED + lg * 8;
    #pragma unroll
    for (int kt = 0; kt < 4; ++kt)
      a[kt] = *reinterpret_cast<const half8*>(ap + kt * 32);
  }

  // phase M: M[16 x 64(half)] -> swizzled LDS stripe
  #pragma unroll
  for (int t = 0; t < 4; ++t) {
    f32x4 acc = {0.f, 0.f, 0.f, 0.f};
    int col = ch * 64 + t * 16 + lr;
    const f16* bp = mWt + (size_t)col * ED + lg * 8;
    #pragma unroll
    for (int kt = 0; kt < 4; ++kt) {
      half8 b = *reinterpret_cast<const half8*>(bp + kt * 32);
      acc = __builtin_amdgcn_mfma_f32_16x16x32_f16(a[kt], b, acc, 0, 0, 0);
    }
    float bias = mb[col];
    #pragma unroll
    for (int j = 0; j < 4; ++j) {
      int srow = lg * 4 + j;   // row within stripe
      int byte = (rs * 16 + srow) * 256 + (((col * 2) ^ ((srow & 7) << 4)));
      *reinterpret_cast<f16*>(Msb + byte) = (f16)tanhf(acc[j] + bias);
    }
  }
  __syncthreads();

  half8 ma[4];
  {
    #pragma unroll
    for (int kt = 0; kt < 4; ++kt) {
      int byte = (rs * 16 + lr) * 256 + ((lg * 16 + kt * 64) ^ ((lr & 7) << 4));
      ma[kt] = *reinterpret_cast<const half8*>(Msb + byte);
    }
  }

  // phase G: w = exp(M@gW + gb)
  float wreg[4][4];
  #pragma unroll
  for (int t = 0; t < 4; ++t) {
    f32x4 acc = {0.f, 0.f, 0.f, 0.f};
    int col = ch * 64 + t * 16 + lr;
    const f16* bp = gWt + (size_t)col * ED + lg * 8;
    #pragma unroll
    for (int kt = 0; kt < 4; ++kt) {
      half8 b = *reinterpret_cast<const half8*>(bp + kt * 32);
      acc = __builtin_amdgcn_mfma_f32_16x16x32_f16(ma[kt], b, acc, 0, 0, 0);
    }
    float bias = gb[col];
    #pragma unroll
    for (int j = 0; j < 4; ++j) {
      float ww = fminf(__expf(acc[j] + bias), 60000.f);
      wreg[t][j] = ww;
      int grow = r0 + lg * 4 + j;
      if (grow < n) P[(size_t)grow * PROW + col] = (f16)ww;
    }
  }

  // phase V: wv = w * tanh(M@aW + ab)
  #pragma unroll
  for (int t = 0; t < 4; ++t) {
    f32x4 acc = {0.f, 0.f, 0.f, 0.f};
    int col = ch * 64 + t * 16 + lr;
    const f16* bp = aWt + (size_t)col * ED + lg * 8;
    #pragma unroll
    for (int kt = 0; kt < 4; ++kt) {
      half8 b = *reinterpret_cast<const half8*>(bp + kt * 32);
      acc = __builtin_amdgcn_mfma_f32_16x16x32_f16(ma[kt], b, acc, 0, 0, 0);
    }
    float bias = ab[col];
    #pragma unroll
    for (int j = 0; j < 4; ++j) {
      int grow = r0 + lg * 4 + j;
      if (grow < n)
        P[(size_t)grow * PROW + 128 + col] = (f16)(wreg[t][j] * tanhf(acc[j] + bias));
    }
  }
}

// ---------------- fused upd + MGV (layers 1,2) ----------------
__global__ __launch_bounds__(256) void updmgv_kernel(
    const f16* __restrict__ h, const f16* __restrict__ ag,
    const f16* __restrict__ uWt, const float* __restrict__ ub,
    const f16* __restrict__ mWt, const float* __restrict__ mb,
    const f16* __restrict__ gWt, const float* __restrict__ gb,
    const f16* __restrict__ aWt, const float* __restrict__ ab,
    f16* __restrict__ hout, f16* __restrict__ P, int n) {
  __shared__ f16 Hs[32 * 128];
  __shared__ f16 Ms[32 * 128];
  char* Hsb = reinterpret_cast<char*>(Hs);
  char* Msb = reinterpret_cast<char*>(Ms);
  const int tid = threadIdx.x;
  const int w = tid >> 6, lane = tid & 63;
  const int rs = w >> 1, ch = w & 1;
  const int lr = lane & 15;
  const int lg = lane >> 4;
  const int r0 = blockIdx.x * 32 + rs * 16;

  half8 ah[4], aa[4];
  {
    int rr = r0 + lr;
    if (rr >= n) rr = n - 1;
    const f16* ap = h + (size_t)rr * ED + lg * 8;
    const f16* bp = ag + (size_t)rr * ED + lg * 8;
    #pragma unroll
    for (int kt = 0; kt < 4; ++kt) {
      ah[kt] = *reinterpret_cast<const half8*>(ap + kt * 32);
      aa[kt] = *reinterpret_cast<const half8*>(bp + kt * 32);
    }
  }

  // phase U: h_new[16 x 64(half)] -> global + swizzled LDS
  #pragma unroll
  for (int t = 0; t < 4; ++t) {
    f32x4 acc = {0.f, 0.f, 0.f, 0.f};
    int col = ch * 64 + t * 16 + lr;
    const f16* bp = uWt + (size_t)col * 256 + lg * 8;
    #pragma unroll
    for (int kt = 0; kt < 4; ++kt) {
      half8 b = *reinterpret_cast<const half8*>(bp + kt * 32);
      acc = __builtin_amdgcn_mfma_f32_16x16x32_f16(ah[kt], b, acc, 0, 0, 0);
    }
    #pragma unroll
    for (int kt = 0; kt < 4; ++kt) {
      half8 b = *reinterpret_cast<const half8*>(bp + 128 + kt * 32);
      acc = __builtin_amdgcn_mfma_f32_16x16x32_f16(aa[kt], b, acc, 0, 0, 0);
    }
    float bias = ub[col];
    #pragma unroll
    for (int j = 0; j < 4; ++j) {
      f16 hv = (f16)tanhf(acc[j] + bias);
      int srow = lg * 4 + j;
      int byte = (rs * 16 + srow) * 256 + (((col * 2) ^ ((srow & 7) << 4)));
      *reinterpret_cast<f16*>(Hsb + byte) = hv;
      int grow = r0 + srow;
      if (grow < n) hout[(size_t)grow * ED + col] = hv;
    }
  }
  __syncthreads();

  half8 ha[4];
  {
    #pragma unroll
    for (int kt = 0; kt < 4; ++kt) {
      int byte = (rs * 16 + lr) * 256 + ((lg * 16 + kt * 64) ^ ((lr & 7) << 4));
      ha[kt] = *reinterpret_cast<const half8*>(Hsb + byte);
    }
  }

  // phase M
  #pragma unroll
  for (int t = 0; t < 4; ++t) {
    f32x4 acc = {0.f, 0.f, 0.f, 0.f};
    int col = ch * 64 + t * 16 + lr;
    const f16* bp = mWt + (size_t)col * ED + lg * 8;
    #pragma unroll
    for (int kt = 0; kt < 4; ++kt) {
      half8 b = *reinterpret_cast<const half8*>(bp + kt * 32);
      acc = __builtin_amdgcn_mfma_f32_16x16x32_f16(ha[kt], b, acc, 0, 0, 0);
    }
    float bias = mb[col];
    #pragma unroll
    for (int j = 0; j < 4; ++j) {
      int srow = lg * 4 + j;
      int byte = (rs * 16 + srow) * 256 + (((col * 2) ^ ((srow & 7) << 4)));
      *reinterpret_cast<f16*>(Msb + byte) = (f16)tanhf(acc[j] + bias);
    }
  }
  __syncthreads();

  half8 ma[4];
  {
    #pragma unroll
    for (int kt = 0; kt < 4; ++kt) {
      int byte = (rs * 16 + lr) * 256 + ((lg * 16 + kt * 64) ^ ((lr & 7) << 4));
      ma[kt] = *reinterpret_cast<const half8*>(Msb + byte);
    }
  }

  // phase G
  float wreg[4][4];
  #pragma unroll
  for (int t = 0; t < 4; ++t) {
    f32x4 acc = {0.f, 0.f, 0.f, 0.f};
    int col = ch * 64 + t * 16 + lr;
    const f16* bp = gWt + (size_t)col * ED + lg * 8;
    #pragma unroll
    for (int kt = 0; kt < 4; ++kt) {
      half8 b = *reinterpret_cast<const half8*>(bp + kt * 32);
      acc = __builtin_amdgcn_mfma_f32_16x16x32_f16(ma[kt], b, acc, 0, 0, 0);
    }
    float bias = gb[col];
    #pragma unroll
    for (int j = 0; j < 4; ++j) {
      float ww = fminf(__expf(acc[j] + bias), 60000.f);
      wreg[t][j] = ww;
      int grow = r0 + lg * 4 + j;
      if (grow < n) P[(size_t)grow * PROW + col] = (f16)ww;
    }
  }

  // phase V
  #pragma unroll
  for (int t = 0; t < 4; ++t) {
    f32x4 acc = {0.f, 0.f, 0.f, 0.f};
    int col = ch * 64 + t * 16 + lr;
    const f16* bp = aWt + (size_t)col * ED + lg * 8;
    #pragma unroll
    for (int kt = 0; kt < 4; ++kt) {
      half8 b = *reinterpret_cast<const half8*>(bp + kt * 32);
      acc = __builtin_amdgcn_mfma_f32_16x16x32_f16(ma[kt], b, acc, 0, 0, 0);
    }
    float bias = ab[col];
    #pragma unroll
    for (int j = 0; j < 4; ++j) {
      int grow = r0 + lg * 4 + j;
      if (grow < n)
        P[(size_t)grow * PROW + 128 + col] = (f16)(wreg[t][j] * tanhf(acc[j] + bias));
    }
  }
}

// ---------------- fused upd + decoder (layer 2 end) ----------------
__global__ __launch_bounds__(256) void upddec_kernel(
    const f16* __restrict__ h, const f16* __restrict__ ag,
    const f16* __restrict__ uWt, const float* __restrict__ ub,
    const f16* __restrict__ d1Wt, const float* __restrict__ d1b,
    const float* __restrict__ d2W, const float* __restrict__ d2b,
    float* __restrict__ out, int n) {
  __shared__ f16 Hs[32 * 128];
  __shared__ float partial[2][2][4][4];   // [rs][ch][lg][j]
  char* Hsb = reinterpret_cast<char*>(Hs);
  const int tid = threadIdx.x;
  const int w = tid >> 6, lane = tid & 63;
  const int rs = w >> 1, ch = w & 1;
  const int lr = lane & 15;
  const int lg = lane >> 4;
  const int r0 = blockIdx.x * 32 + rs * 16;

  half8 ah[4], aa[4];
  {
    int rr = r0 + lr;
    if (rr >= n) rr = n - 1;
    const f16* ap = h + (size_t)rr * ED + lg * 8;
    const f16* bp = ag + (size_t)rr * ED + lg * 8;
    #pragma unroll
    for (int kt = 0; kt < 4; ++kt) {
      ah[kt] = *reinterpret_cast<const half8*>(ap + kt * 32);
      aa[kt] = *reinterpret_cast<const half8*>(bp + kt * 32);
    }
  }

  // phase U: h3 -> swizzled LDS only
  #pragma unroll
  for (int t = 0; t < 4; ++t) {
    f32x4 acc = {0.f, 0.f, 0.f, 0.f};
    int col = ch * 64 + t * 16 + lr;
    const f16* bp = uWt + (size_t)col * 256 + lg * 8;
    #pragma unroll
    for (int kt = 0; kt < 4; ++kt) {
      half8 b = *reinterpret_cast<const half8*>(bp + kt * 32);
      acc = __builtin_amdgcn_mfma_f32_16x16x32_f16(ah[kt], b, acc, 0, 0, 0);
    }
    #pragma unroll
    for (int kt = 0; kt < 4; ++kt) {
      half8 b = *reinterpret_cast<const half8*>(bp + 128 + kt * 32);
      acc = __builtin_amdgcn_mfma_f32_16x16x32_f16(aa[kt], b, acc, 0, 0, 0);
    }
    float bias = ub[col];
    #pragma unroll
    for (int j = 0; j < 4; ++j) {
      int srow = lg * 4 + j;
      int byte = (rs * 16 + srow) * 256 + (((col * 2) ^ ((srow & 7) << 4)));
      *reinterpret_cast<f16*>(Hsb + byte) = (f16)tanhf(acc[j] + bias);
    }
  }
  __syncthreads();

  half8 ha[4];
  {
    #pragma unroll
    for (int kt = 0; kt < 4; ++kt) {
      int byte = (rs * 16 + lr) * 256 + ((lg * 16 + kt * 64) ^ ((lr & 7) << 4));
      ha[kt] = *reinterpret_cast<const half8*>(Hsb + byte);
    }
  }

  // decoder: each wave does 32 of the 64 d1 cols
  float rowsum[4] = {0.f, 0.f, 0.f, 0.f};
  #pragma unroll
  for (int t = 0; t < 2; ++t) {
    f32x4 acc = {0.f, 0.f, 0.f, 0.f};
    int col = ch * 32 + t * 16 + lr;
    const f16* bp = d1Wt + (size_t)col * ED + lg * 8;
    #pragma unroll
    for (int kt = 0; kt < 4; ++kt) {
      half8 b = *reinterpret_cast<const half8*>(bp + kt * 32);
      acc = __builtin_amdgcn_mfma_f32_16x16x32_f16(ha[kt], b, acc, 0, 0, 0);
    }
    float b1 = d1b[col], w2 = d2W[col];
    #pragma unroll
    for (int j = 0; j < 4; ++j) rowsum[j] += tanhf(acc[j] + b1) * w2;
  }
  #pragma unroll
  for (int d = 1; d < 16; d <<= 1) {
    #pragma unroll
    for (int j = 0; j < 4; ++j) rowsum[j] += __shfl_xor(rowsum[j], d, 64);
  }
  if (lr == 0) {
    #pragma unroll
    for (int j = 0; j < 4; ++j) partial[rs][ch][lg][j] = rowsum[j];
  }
  __syncthreads();
  if (ch == 0 && lr == 0) {
    #pragma unroll
    for (int j = 0; j < 4; ++j) {
      int grow = r0 + lg * 4 + j;
      if (grow < n)
        out[grow] = partial[rs][0][lg][j] + partial[rs][1][lg][j] + d2b[0];
    }
  }
}

// ---------------- edge aggregation: one wave per dst node, pure gather-sum ---
__global__ __launch_bounds__(256) void edge_aggr_kernel(
    const int* __restrict__ offs, const int* __restrict__ ssrc,
    const f16* __restrict__ P, f16* __restrict__ aggr, int n) {
  int i = blockIdx.x * 4 + (threadIdx.x >> 6);
  if (i >= n) return;
  int lane = threadIdx.x & 63;
  int s0 = offs[i], s1 = offs[i + 1];
  const char* Pb = reinterpret_cast<const char*>(P);

  float4 acc = {0.f, 0.f, 0.f, 0.f};
  #pragma unroll 4
  for (int e = s0; e < s1; ++e) {
    int sn = ssrc[e];
    half4 x = *reinterpret_cast<const half4*>(Pb + (size_t)sn * 512 + lane * 8);
    acc.x += (float)x.x;
    acc.y += (float)x.y;
    acc.z += (float)x.z;
    acc.w += (float)x.w;
  }
  float px = __shfl(acc.x, lane ^ 32, 64);
  float py = __shfl(acc.y, lane ^ 32, 64);
  float pz = __shfl(acc.z, lane ^ 32, 64);
  float pw = __shfl(acc.w, lane ^ 32, 64);
  if (lane >= 32) {
    half4 o;
    o.x = (f16)(acc.x / (px + 1e-16f));
    o.y = (f16)(acc.y / (py + 1e-16f));
    o.z = (f16)(acc.z / (pz + 1e-16f));
    o.w = (f16)(acc.w / (pw + 1e-16f));
    *reinterpret_cast<half4*>(
        reinterpret_cast<char*>(aggr) + (size_t)i * 256 + (size_t)(lane - 32) * 8) = o;
  }
}

// ---------------- host ----------------
extern "C" void kernel_launch(void* const* d_in, const int* in_sizes, int n_in,
                              void* d_out, int out_size, void* d_ws, size_t ws_size,
                              hipStream_t stream) {
  const float* node_feature = (const float*)d_in[0];
  const int*   edge_index   = (const int*)d_in[1];
  const float* enc_W  = (const float*)d_in[3];
  const float* enc_b  = (const float*)d_in[4];
  const float* gate_W = (const float*)d_in[5];
  const float* gate_b = (const float*)d_in[6];
  const float* att_W  = (const float*)d_in[7];
  const float* att_b  = (const float*)d_in[8];
  const float* msg_W  = (const float*)d_in[9];
  const float* msg_b  = (const float*)d_in[10];
  const float* upd_W  = (const float*)d_in[11];
  const float* upd_b  = (const float*)d_in[12];
  const float* dec1_W = (const float*)d_in[13];
  const float* dec1_b = (const float*)d_in[14];
  const float* dec2_W = (const float*)d_in[15];
  const float* dec2_b = (const float*)d_in[16];

  const int n = in_sizes[0] / 2;   // 50000
  const int E = in_sizes[1] / 2;   // 800000
  const int* src = edge_index;
  const int* dst = edge_index + E;

  char* ws = (char*)d_ws;
  size_t off = 0;
  auto alloc = [&](size_t bytes) -> void* {
    void* p = ws + off;
    off += (bytes + 255) & ~(size_t)255;
    return p;
  };
  f16* hA   = (f16*)alloc((size_t)n * ED * 2);
  f16* hB   = (f16*)alloc((size_t)n * ED * 2);
  f16* P    = (f16*)alloc((size_t)n * PROW * 2);
  f16* aggr = (f16*)alloc((size_t)n * ED * 2);
  int* deg    = (int*)alloc((size_t)n * 4);
  int* offs   = (int*)alloc((size_t)(n + 1) * 4);
  int* cursor = (int*)alloc((size_t)n * 4);
  int* ssrc   = (int*)alloc((size_t)E * 4);
  f16* msgT  = (f16*)alloc((size_t)3 * ED * ED * 2);
  f16* gateT = (f16*)alloc((size_t)3 * ED * ED * 2);
  f16* attT  = (f16*)alloc((size_t)3 * ED * ED * 2);
  f16* updT  = (f16*)alloc((size_t)3 * ED * 2 * ED * 2);
  f16* dec1T = (f16*)alloc((size_t)ED * 64 * 2);

  // weight prep (once per call)
  {
    int tot3 = 3 * 3 * ED * ED;
    transpose3_kernel<<<(tot3 + 255) / 256, 256, 0, stream>>>(
        msg_W, gate_W, att_W, msgT, gateT, attT);
    int totu = 3 * 2 * ED * ED;
    transpose_w_kernel<<<(totu + 255) / 256, 256, 0, stream>>>(
        upd_W, updT, 2 * ED, ED, totu);
    int totd = ED * 64;
    transpose_w_kernel<<<(totd + 255) / 256, 256, 0, stream>>>(
        dec1_W, dec1T, ED, 64, totd);
  }

  // CSR build (once per call)
  hipMemsetAsync(deg, 0, (size_t)n * 4, stream);
  count_deg_kernel<<<(E + 255) / 256, 256, 0, stream>>>(dst, deg, E);
  scan_kernel<<<1, 1024, 0, stream>>>(deg, offs, cursor, n);
  scatter_kernel<<<(E + 255) / 256, 256, 0, stream>>>(src, dst, cursor, ssrc, E);

  // encoder
  encoder_kernel<<<((size_t)n * ED + 255) / 256, 256, 0, stream>>>(
      node_feature, enc_W, enc_b, hA, n);

  const int gemm_grid = (n + 31) / 32;
  const int aggr_grid = (n + 3) / 4;

  // layer 0 MGV
  gemm_mgv_kernel<<<gemm_grid, 256, 0, stream>>>(
      hA, msgT, msg_b, gateT, gate_b, attT, att_b, P, n);
  edge_aggr_kernel<<<aggr_grid, 256, 0, stream>>>(offs, ssrc, P, aggr, n);

  // upd0 + MGV1
  updmgv_kernel<<<gemm_grid, 256, 0, stream>>>(
      hA, aggr, updT, upd_b,
      msgT + (size_t)1 * ED * ED, msg_b + ED,
      gateT + (size_t)1 * ED * ED, gate_b + ED,
      attT + (size_t)1 * ED * ED, att_b + ED,
      hB, P, n);
  edge_aggr_kernel<<<aggr_grid, 256, 0, stream>>>(offs, ssrc, P, aggr, n);

  // upd1 + MGV2
  updmgv_kernel<<<gemm_grid, 256, 0, stream>>>(
      hB, aggr, updT + (size_t)1 * 2 * ED * ED, upd_b + ED,
      msgT + (size_t)2 * ED * ED, msg_b + 2 * ED,
      gateT + (size_t)2 * ED * ED, gate_b + 2 * ED,
      attT + (size_t)2 * ED * ED, att_b + 2 * ED,
      hA, P, n);
  edge_aggr_kernel<<<aggr_grid, 256, 0, stream>>>(offs, ssrc, P, aggr, n);

  // upd2 + decoder
  upddec_kernel<<<gemm_grid, 256, 0, stream>>>(
      hA, aggr, updT + (size_t)2 * 2 * ED * ED, upd_b + 2 * ED,
      dec1T, dec1_b, dec2_W, dec2_b, (float*)d_out, n);
}